// Round 1
// baseline (1921.900 us; speedup 1.0000x reference)
//
#include <hip/hip_runtime.h>
#include <hip/hip_bf16.h>
#include <math.h>

#define B_    4
#define H_    48
#define W_    48
#define N_    2304
#define C_    512
#define NH_   8
#define HD_   64
#define LKV_  684
#define QB_   16
#define SORTN 4096

// ---------------- GEMM (NT): C[m,n] = (A[m,:] (+A2[m,:])) . Bw[n,:] + bias[n]
__global__ __launch_bounds__(256) void gemm_nt(
    const float* __restrict__ A, const float* __restrict__ A2,
    const float* __restrict__ Bw, const float* __restrict__ bias,
    float* __restrict__ Cc, int M, int Nn, int K)
{
  __shared__ float As[64][17];
  __shared__ float Bs[64][17];
  const int tid  = threadIdx.x;
  const int row0 = blockIdx.x * 64, col0 = blockIdx.y * 64;
  const int tm = tid >> 4, tn = tid & 15;
  const int lr = tid >> 2;          // 0..63
  const int lc = (tid & 3) << 2;    // 0,4,8,12
  float acc[4][4] = {};
  for (int k0 = 0; k0 < K; k0 += 16) {
    int gr = row0 + lr;
    float4 va = make_float4(0.f, 0.f, 0.f, 0.f);
    if (gr < M) {
      va = *(const float4*)(A + (size_t)gr * K + k0 + lc);
      if (A2) {
        float4 w = *(const float4*)(A2 + (size_t)gr * K + k0 + lc);
        va.x += w.x; va.y += w.y; va.z += w.z; va.w += w.w;
      }
    }
    As[lr][lc] = va.x; As[lr][lc+1] = va.y; As[lr][lc+2] = va.z; As[lr][lc+3] = va.w;
    float4 vb = *(const float4*)(Bw + (size_t)(col0 + lr) * K + k0 + lc);
    Bs[lr][lc] = vb.x; Bs[lr][lc+1] = vb.y; Bs[lr][lc+2] = vb.z; Bs[lr][lc+3] = vb.w;
    __syncthreads();
    #pragma unroll
    for (int kk = 0; kk < 16; ++kk) {
      float a0[4], b0[4];
      #pragma unroll
      for (int i = 0; i < 4; ++i) a0[i] = As[tm * 4 + i][kk];
      #pragma unroll
      for (int j = 0; j < 4; ++j) b0[j] = Bs[tn * 4 + j][kk];
      #pragma unroll
      for (int i = 0; i < 4; ++i)
        #pragma unroll
        for (int j = 0; j < 4; ++j) acc[i][j] += a0[i] * b0[j];
    }
    __syncthreads();
  }
  #pragma unroll
  for (int i = 0; i < 4; ++i) {
    int gr = row0 + tm * 4 + i;
    if (gr >= M) continue;
    #pragma unroll
    for (int j = 0; j < 4; ++j) {
      int gc = col0 + tn * 4 + j;
      Cc[(size_t)gr * Nn + gc] = acc[i][j] + bias[gc];
    }
  }
}

// ---------------- depthwise 3x3 conv, channel-last layout [B,H,W,C]
__global__ __launch_bounds__(256) void dwconv_kernel(
    const float* __restrict__ lin, const float* __restrict__ cw,
    const float* __restrict__ cb, float* __restrict__ outp)
{
  size_t gid = (size_t)blockIdx.x * blockDim.x + threadIdx.x;
  if (gid >= (size_t)B_ * N_ * C_) return;
  int c = (int)(gid % C_);
  size_t t = gid / C_;
  int wv = (int)(t % W_);
  size_t r = t / W_;
  int hv = (int)(r % H_);
  int b  = (int)(r / H_);
  float acc = cb[c];
  const float* wgt = cw + c * 9;
  #pragma unroll
  for (int dy = 0; dy < 3; ++dy) {
    int hh = hv + dy - 1;
    if (hh < 0 || hh >= H_) continue;
    #pragma unroll
    for (int dx = 0; dx < 3; ++dx) {
      int ww = wv + dx - 1;
      if (ww < 0 || ww >= W_) continue;
      acc += wgt[dy * 3 + dx] * lin[(((size_t)b * H_ + hh) * W_ + ww) * C_ + c];
    }
  }
  outp[gid] = acc;
}

// ---------------- stable argsort (ascending) of one row of 2304 floats
__global__ __launch_bounds__(256) void argsort_kernel(
    const float* __restrict__ mask, int* __restrict__ idx_out)
{
  __shared__ float key[SORTN];
  __shared__ int   kid[SORTN];
  const int row = blockIdx.x;
  const float* m = mask + (size_t)row * N_;
  for (int i = threadIdx.x; i < SORTN; i += 256) {
    key[i] = (i < N_) ? m[i] : INFINITY;
    kid[i] = i;
  }
  __syncthreads();
  for (int k = 2; k <= SORTN; k <<= 1) {
    for (int j = k >> 1; j > 0; j >>= 1) {
      for (int i = threadIdx.x; i < SORTN; i += 256) {
        int ixj = i ^ j;
        if (ixj > i) {
          float a = key[i], b = key[ixj];
          int ia = kid[i], ib = kid[ixj];
          bool up = ((i & k) == 0);
          bool sw = up ? (b < a || (b == a && ib < ia))
                       : (a < b || (a == b && ia < ib));
          if (sw) { key[i] = b; key[ixj] = a; kid[i] = ib; kid[ixj] = ia; }
        }
      }
      __syncthreads();
    }
  }
  for (int i = threadIdx.x; i < N_; i += 256) idx_out[(size_t)row * N_ + i] = kid[i];
}

// ---------------- pooled sequence: seq[b,l,c], one block per (b,l)
__global__ __launch_bounds__(256) void pool_kernel(
    const float* __restrict__ ctx, const int* __restrict__ idx,
    const float* __restrict__ f1w, const float* __restrict__ f1b,
    const float* __restrict__ f2w, const float* __restrict__ f2b,
    float* __restrict__ seq, int transposed)
{
  int bl = blockIdx.x;
  int b = bl / LKV_, l = bl % LKV_;
  const int* id = idx + (size_t)b * N_;
  int j0, cnt;
  const float* fw; float fb;
  if (l < 12)       { j0 = l * 48;              cnt = 48; fw = f1w; fb = f1b[0]; }
  else if (l < 108) { j0 = 576 + (l - 12) * 12; cnt = 12; fw = f2w; fb = f2b[0]; }
  else              { j0 = 1728 + (l - 108);    cnt = 1;  fw = nullptr; fb = 0.f; }
  int c0 = threadIdx.x, c1 = threadIdx.x + 256;
  float a0 = fb, a1 = fb;
  for (int r = 0; r < cnt; ++r) {
    int n = id[j0 + r];
    if (transposed) n = (n % 48) * 48 + n / 48;   // ctx_t[m] = ctx[(m%H)*W + m/H]
    const float* src = ctx + ((size_t)b * N_ + n) * C_;
    float wr = fw ? fw[r] : 1.f;
    a0 += wr * src[c0];
    a1 += wr * src[c1];
  }
  float* dst = seq + ((size_t)b * LKV_ + l) * C_;
  dst[c0] = a0; dst[c1] = a1;
}

// ---------------- attention: one block = (b, h, 16 queries)
__global__ __launch_bounds__(256) void attn_kernel(
    const float* __restrict__ q, const float* __restrict__ kv1,
    const float* __restrict__ kv2, float* __restrict__ outbuf)
{
  __shared__ float S[QB_][LKV_];     // 43.8 KB
  __shared__ float qs[QB_][HD_ + 1]; // padded: avoid 16-way bank conflict
  __shared__ float rinv[QB_];
  const int blk = blockIdx.x;
  const int qb = blk % (N_ / QB_);
  const int bh = blk / (N_ / QB_);
  const int h = bh % NH_, b = bh / NH_;
  const int tid = threadIdx.x;

  for (int i = tid; i < QB_ * HD_; i += 256) {
    int qi = i / HD_, d = i % HD_;
    qs[qi][d] = q[((size_t)b * N_ + qb * QB_ + qi) * C_ + h * HD_ + d];
  }
  __syncthreads();

  const float* kvsrc = (h < 4) ? kv1 : kv2;
  const int hcol = (h & 3) * HD_;

  // pass 1: scores
  for (int i = tid; i < QB_ * LKV_; i += 256) {
    int l = i / QB_, qi = i % QB_;
    const float* krow = kvsrc + ((size_t)b * LKV_ + l) * C_ + hcol;
    float s = 0.f;
    #pragma unroll
    for (int d = 0; d < HD_; ++d) s += qs[qi][d] * krow[d];
    S[qi][l] = s * 0.125f;
  }
  __syncthreads();

  // pass 2: per-row max / exp / sum (16 lanes per query, contiguous in wave)
  {
    const int g = tid >> 4, lane = tid & 15;
    float mx = -INFINITY;
    for (int l = lane; l < LKV_; l += 16) mx = fmaxf(mx, S[g][l]);
    #pragma unroll
    for (int off = 8; off >= 1; off >>= 1) mx = fmaxf(mx, __shfl_xor(mx, off, 16));
    float ssum = 0.f;
    for (int l = lane; l < LKV_; l += 16) {
      float e = __expf(S[g][l] - mx);
      S[g][l] = e;
      ssum += e;
    }
    #pragma unroll
    for (int off = 8; off >= 1; off >>= 1) ssum += __shfl_xor(ssum, off, 16);
    if (lane == 0) rinv[g] = 1.f / ssum;
  }
  __syncthreads();

  // pass 3: out = P . V / sum
  {
    const int d = tid & 63, ig = tid >> 6;
    #pragma unroll
    for (int rep = 0; rep < 4; ++rep) {
      int qi = ig * 4 + rep;
      float acc = 0.f;
      for (int l = 0; l < LKV_; ++l) {
        const float* vrow = kvsrc + ((size_t)b * LKV_ + l) * C_ + 256 + hcol;
        acc += S[qi][l] * vrow[d];
      }
      outbuf[((size_t)b * N_ + qb * QB_ + qi) * C_ + h * HD_ + d] = acc * rinv[qi];
    }
  }
}

extern "C" void kernel_launch(void* const* d_in, const int* in_sizes, int n_in,
                              void* d_out, int out_size, void* d_ws, size_t ws_size,
                              hipStream_t stream)
{
  const float* x      = (const float*)d_in[0];
  const float* ctx    = (const float*)d_in[1];
  const float* mask1  = (const float*)d_in[2];
  const float* mask2  = (const float*)d_in[3];
  const float* q_w    = (const float*)d_in[4];
  const float* q_b    = (const float*)d_in[5];
  const float* kv1_w  = (const float*)d_in[6];
  const float* kv1_b  = (const float*)d_in[7];
  const float* kv2_w  = (const float*)d_in[8];
  const float* kv2_b  = (const float*)d_in[9];
  const float* f1_w   = (const float*)d_in[10];
  const float* f1_b   = (const float*)d_in[11];
  const float* f2_w   = (const float*)d_in[12];
  const float* f2_b   = (const float*)d_in[13];
  const float* lepe_w = (const float*)d_in[14];
  const float* lepe_b = (const float*)d_in[15];
  const float* lcw    = (const float*)d_in[16];
  const float* lcb    = (const float*)d_in[17];
  const float* proj_w = (const float*)d_in[18];
  const float* proj_b = (const float*)d_in[19];
  float* outp = (float*)d_out;

  char* ws = (char*)d_ws;
  float* bufA = (float*)(ws);               // lepe_lin, later attn out   (18.9 MB)
  float* bufB = (float*)(ws + 18874368);    // lepe                       (18.9 MB)
  float* bufQ = (float*)(ws + 37748736);    // q                          (18.9 MB)
  float* seq1 = (float*)(ws + 56623104);    // [B,684,C]                  (5.6 MB)
  float* seq2 = (float*)(ws + 62226432);
  float* kv1o = (float*)(ws + 67829760);    // [B*684, 512]
  float* kv2o = (float*)(ws + 73433088);
  int*   idx1 = (int*)  (ws + 79036416);
  int*   idx2 = (int*)  (ws + 79073280);

  dim3 blk(256);
  // 1. lepe linear + depthwise conv
  gemm_nt<<<dim3(144, 8), blk, 0, stream>>>(x, nullptr, lepe_w, lepe_b, bufA, B_ * N_, C_, C_);
  dwconv_kernel<<<dim3((B_ * N_ * C_ + 255) / 256), blk, 0, stream>>>(bufA, lcw, lcb, bufB);
  // 2. stable argsorts
  argsort_kernel<<<dim3(B_), blk, 0, stream>>>(mask1, idx1);
  argsort_kernel<<<dim3(B_), blk, 0, stream>>>(mask2, idx2);
  // 3. pooled sequences
  pool_kernel<<<dim3(B_ * LKV_), blk, 0, stream>>>(ctx, idx1, f1_w, f1_b, f2_w, f2_b, seq1, 0);
  pool_kernel<<<dim3(B_ * LKV_), blk, 0, stream>>>(ctx, idx2, f1_w, f1_b, f2_w, f2_b, seq2, 1);
  // 4. projections
  gemm_nt<<<dim3(43, 8), blk, 0, stream>>>(seq1, nullptr, kv1_w, kv1_b, kv1o, B_ * LKV_, C_, C_);
  gemm_nt<<<dim3(43, 8), blk, 0, stream>>>(seq2, nullptr, kv2_w, kv2_b, kv2o, B_ * LKV_, C_, C_);
  gemm_nt<<<dim3(144, 8), blk, 0, stream>>>(x, nullptr, q_w, q_b, bufQ, B_ * N_, C_, C_);
  // 5. attention (writes into bufA, already consumed by conv)
  attn_kernel<<<dim3(B_ * NH_ * (N_ / QB_)), blk, 0, stream>>>(bufQ, kv1o, kv2o, bufA);
  // 6. final projection with fused (+lepe)
  gemm_nt<<<dim3(144, 8), blk, 0, stream>>>(bufA, bufB, proj_w, proj_b, outp, B_ * N_, C_, C_);
}

// Round 2
// 406.597 us; speedup vs baseline: 4.7268x; 4.7268x over previous
//
#include <hip/hip_runtime.h>
#include <hip/hip_bf16.h>
#include <math.h>

#define B_    4
#define H_    48
#define W_    48
#define N_    2304
#define C_    512
#define NH_   8
#define HD_   64
#define LKV_  684
#define LKP_  704      // padded kv length (11 * 64)
#define SORTN 4096

typedef __attribute__((ext_vector_type(8))) short short8;
typedef __attribute__((ext_vector_type(4))) float f32x4;

#define MFMA16(a, b, c) __builtin_amdgcn_mfma_f32_16x16x32_bf16(a, b, c, 0, 0, 0)

__device__ __forceinline__ unsigned short f2bf(float f) {
  __hip_bfloat16 h = __float2bfloat16(f);
  return *reinterpret_cast<unsigned short*>(&h);
}

// ---------------- fp32 -> bf16 pack with scale (n multiple of 4)
__global__ __launch_bounds__(256) void pack_bf16(
    const float* __restrict__ in, unsigned short* __restrict__ out, int n, float scale)
{
  int i = (blockIdx.x * 256 + threadIdx.x) * 4;
  if (i >= n) return;
  float4 v = *(const float4*)(in + i);
  ushort4 o;
  o.x = f2bf(v.x * scale); o.y = f2bf(v.y * scale);
  o.z = f2bf(v.z * scale); o.w = f2bf(v.w * scale);
  *(ushort4*)(out + i) = o;
}

// ---------------- (a+b) -> bf16 pack
__global__ __launch_bounds__(256) void addpack_bf16(
    const float* __restrict__ a, const float* __restrict__ b,
    unsigned short* __restrict__ out, int n)
{
  int i = (blockIdx.x * 256 + threadIdx.x) * 4;
  if (i >= n) return;
  float4 va = *(const float4*)(a + i);
  float4 vb = *(const float4*)(b + i);
  ushort4 o;
  o.x = f2bf(va.x + vb.x); o.y = f2bf(va.y + vb.y);
  o.z = f2bf(va.z + vb.z); o.w = f2bf(va.w + vb.w);
  *(ushort4*)(out + i) = o;
}

// ---------------- bf16 MFMA GEMM (NT): out[m,n] = A[m,:] . Bw[n,:] + bias[n]
// A: [M][K] bf16 (M padded to 128), Bw: [N][K] bf16, tile 128x128, BK=32.
__global__ __launch_bounds__(256) void gemm_bf16(
    const unsigned short* __restrict__ A, const unsigned short* __restrict__ Bw,
    const float* __restrict__ bias, void* __restrict__ out,
    int K, int Nn, int out_bf16, float oscale)
{
  __shared__ unsigned short Abuf[128][40];   // pad 32->40: 2-way (free) banks
  __shared__ unsigned short Bbuf[128][40];
  const int tid = threadIdx.x;
  const int l = tid & 63, w = tid >> 6;
  const int wm = w >> 1, wn = w & 1;
  const int lo16 = l & 15, hi = l >> 4;
  const int row0 = blockIdx.x * 128, col0 = blockIdx.y * 128;
  const int srow = tid >> 2, scol = (tid & 3) * 8;

  f32x4 acc[4][4];
  #pragma unroll
  for (int m = 0; m < 4; ++m)
    #pragma unroll
    for (int n = 0; n < 4; ++n)
      #pragma unroll
      for (int r = 0; r < 4; ++r) acc[m][n][r] = 0.f;

  for (int k0 = 0; k0 < K; k0 += 32) {
    uint4 a0 = *(const uint4*)(A + (size_t)(row0 + srow) * K + k0 + scol);
    uint4 a1 = *(const uint4*)(A + (size_t)(row0 + 64 + srow) * K + k0 + scol);
    uint4 b0 = *(const uint4*)(Bw + (size_t)(col0 + srow) * K + k0 + scol);
    uint4 b1 = *(const uint4*)(Bw + (size_t)(col0 + 64 + srow) * K + k0 + scol);
    __syncthreads();                    // previous iter's LDS reads done
    *(uint4*)&Abuf[srow][scol]      = a0;
    *(uint4*)&Abuf[64 + srow][scol] = a1;
    *(uint4*)&Bbuf[srow][scol]      = b0;
    *(uint4*)&Bbuf[64 + srow][scol] = b1;
    __syncthreads();
    short8 af[4], bf[4];
    #pragma unroll
    for (int m = 0; m < 4; ++m)
      af[m] = *(const short8*)&Abuf[wm * 64 + m * 16 + lo16][hi * 8];
    #pragma unroll
    for (int n = 0; n < 4; ++n)
      bf[n] = *(const short8*)&Bbuf[wn * 64 + n * 16 + lo16][hi * 8];
    #pragma unroll
    for (int m = 0; m < 4; ++m)
      #pragma unroll
      for (int n = 0; n < 4; ++n)
        acc[m][n] = MFMA16(af[m], bf[n], acc[m][n]);
  }

  #pragma unroll
  for (int m = 0; m < 4; ++m) {
    #pragma unroll
    for (int n = 0; n < 4; ++n) {
      int gcol = col0 + wn * 64 + n * 16 + lo16;
      #pragma unroll
      for (int r = 0; r < 4; ++r) {
        int grow = row0 + wm * 64 + m * 16 + hi * 4 + r;
        float v = acc[m][n][r] + bias[gcol];
        if (out_bf16)
          ((unsigned short*)out)[(size_t)grow * Nn + gcol] = f2bf(v * oscale);
        else
          ((float*)out)[(size_t)grow * Nn + gcol] = v;
      }
    }
  }
}

// ---------------- depthwise 3x3 conv, channel-last [B,H,W,C] fp32
__global__ __launch_bounds__(256) void dwconv_kernel(
    const float* __restrict__ lin, const float* __restrict__ cw,
    const float* __restrict__ cb, float* __restrict__ outp)
{
  size_t gid = (size_t)blockIdx.x * blockDim.x + threadIdx.x;
  if (gid >= (size_t)B_ * N_ * C_) return;
  int c = (int)(gid % C_);
  size_t t = gid / C_;
  int wv = (int)(t % W_);
  size_t r = t / W_;
  int hv = (int)(r % H_);
  int b  = (int)(r / H_);
  float acc = cb[c];
  const float* wgt = cw + c * 9;
  #pragma unroll
  for (int dy = 0; dy < 3; ++dy) {
    int hh = hv + dy - 1;
    if (hh < 0 || hh >= H_) continue;
    #pragma unroll
    for (int dx = 0; dx < 3; ++dx) {
      int ww = wv + dx - 1;
      if (ww < 0 || ww >= W_) continue;
      acc += wgt[dy * 3 + dx] * lin[(((size_t)b * H_ + hh) * W_ + ww) * C_ + c];
    }
  }
  outp[gid] = acc;
}

// ---------------- stable argsort (ascending); blocks 0-3: mask1, 4-7: mask2
__global__ __launch_bounds__(1024) void argsort_kernel(
    const float* __restrict__ m1, const float* __restrict__ m2,
    int* __restrict__ i1, int* __restrict__ i2)
{
  __shared__ float key[SORTN];
  __shared__ int   kid[SORTN];
  const int row = blockIdx.x & 3;
  const float* m = ((blockIdx.x >> 2) ? m2 : m1) + (size_t)row * N_;
  int* out = ((blockIdx.x >> 2) ? i2 : i1) + (size_t)row * N_;
  for (int i = threadIdx.x; i < SORTN; i += 1024) {
    key[i] = (i < N_) ? m[i] : INFINITY;
    kid[i] = i;
  }
  __syncthreads();
  for (int k = 2; k <= SORTN; k <<= 1) {
    for (int j = k >> 1; j > 0; j >>= 1) {
      for (int i = threadIdx.x; i < SORTN; i += 1024) {
        int ixj = i ^ j;
        if (ixj > i) {
          float a = key[i], b = key[ixj];
          int ia = kid[i], ib = kid[ixj];
          bool up = ((i & k) == 0);
          bool sw = up ? (b < a || (b == a && ib < ia))
                       : (a < b || (a == b && ia < ib));
          if (sw) { key[i] = b; key[ixj] = a; kid[i] = ib; kid[ixj] = ia; }
        }
      }
      __syncthreads();
    }
  }
  for (int i = threadIdx.x; i < N_; i += 1024) out[i] = kid[i];
}

// ---------------- pooled sequence -> bf16, padded per-b layout [B][704][512]
__global__ __launch_bounds__(256) void pool_kernel(
    const float* __restrict__ ctx, const int* __restrict__ idx,
    const float* __restrict__ f1w, const float* __restrict__ f1b,
    const float* __restrict__ f2w, const float* __restrict__ f2b_,
    unsigned short* __restrict__ seqb, int transposed)
{
  int bl = blockIdx.x;
  int b = bl / LKP_, l = bl % LKP_;
  unsigned short* dst = seqb + ((size_t)b * LKP_ + l) * C_;
  int c0 = threadIdx.x, c1 = threadIdx.x + 256;
  if (l >= LKV_) { dst[c0] = 0; dst[c1] = 0; return; }
  const int* id = idx + (size_t)b * N_;
  int j0, cnt;
  const float* fw; float fb;
  if (l < 12)       { j0 = l * 48;              cnt = 48; fw = f1w; fb = f1b[0]; }
  else if (l < 108) { j0 = 576 + (l - 12) * 12; cnt = 12; fw = f2w; fb = f2b_[0]; }
  else              { j0 = 1728 + (l - 108);    cnt = 1;  fw = nullptr; fb = 0.f; }
  float a0 = fb, a1 = fb;
  for (int r = 0; r < cnt; ++r) {
    int n = id[j0 + r];
    if (transposed) n = (n % 48) * 48 + n / 48;
    const float* src = ctx + ((size_t)b * N_ + n) * C_;
    float wr = fw ? fw[r] : 1.f;
    a0 += wr * src[c0];
    a1 += wr * src[c1];
  }
  dst[c0] = f2bf(a0);
  dst[c1] = f2bf(a1);
}

// ---------------- split kv gemm outputs into K [B,8,704,64] (bf16)
__global__ __launch_bounds__(256) void kvpack_k(
    const unsigned short* __restrict__ kv1, const unsigned short* __restrict__ kv2,
    unsigned short* __restrict__ Kb)
{
  int gid = blockIdx.x * 256 + threadIdx.x;   // ordered (b,h,l,d)
  int d = gid & 63;
  int t = gid >> 6;
  int l = t % LKP_;
  int h = (t / LKP_) & 7;
  int b = t / (LKP_ * 8);
  unsigned short val = 0;
  if (l < LKV_) {
    const unsigned short* src = (h < 4) ? kv1 : kv2;
    val = src[((size_t)(b * LKP_ + l)) * C_ + (h & 3) * 64 + d];
  }
  Kb[gid] = val;
}

// ---------------- and V^T [B,8,64,704] (bf16)
__global__ __launch_bounds__(256) void kvpack_v(
    const unsigned short* __restrict__ kv1, const unsigned short* __restrict__ kv2,
    unsigned short* __restrict__ Vtb)
{
  int gid = blockIdx.x * 256 + threadIdx.x;   // ordered (b,h,d,l)
  int l = gid % LKP_;
  int t = gid / LKP_;
  int d = t & 63;
  int h = (t >> 6) & 7;
  int b = t >> 9;
  unsigned short val = 0;
  if (l < LKV_) {
    const unsigned short* src = (h < 4) ? kv1 : kv2;
    val = src[((size_t)(b * LKP_ + l)) * C_ + 256 + (h & 3) * 64 + d];
  }
  Vtb[gid] = val;
}

// ---------------- fused flash attention, bf16 MFMA
// grid: B*NH*(N/64); block 256 = 4 waves, each wave owns 16 q rows.
__global__ __launch_bounds__(256) void attn_kernel(
    const unsigned short* __restrict__ Qb, const unsigned short* __restrict__ Kb,
    const unsigned short* __restrict__ Vtb, float* __restrict__ outp)
{
  __shared__ unsigned short P[4][16][72];   // per-wave P tile, padded stride 144B
  const int tid = threadIdx.x, l = tid & 63, wv = tid >> 6;
  const int lo16 = l & 15, hi = l >> 4;
  const int blk = blockIdx.x;
  const int qb = blk % (N_ / 64);
  const int bh = blk / (N_ / 64);
  const int h = bh & 7, b = bh >> 3;

  const int qrow = qb * 64 + wv * 16 + lo16;
  const unsigned short* qptr = Qb + ((size_t)b * N_ + qrow) * C_ + h * 64;
  short8 qf0 = *(const short8*)(qptr + hi * 8);
  short8 qf1 = *(const short8*)(qptr + 32 + hi * 8);

  const unsigned short* kbase = Kb + (size_t)bh * LKP_ * 64;
  const unsigned short* vbase = Vtb + (size_t)bh * 64 * LKP_;

  float mreg[4], lsum[4];
  f32x4 o[4];
  #pragma unroll
  for (int r = 0; r < 4; ++r) { mreg[r] = -INFINITY; lsum[r] = 0.f; }
  #pragma unroll
  for (int df = 0; df < 4; ++df)
    #pragma unroll
    for (int r = 0; r < 4; ++r) o[df][r] = 0.f;

  for (int t = 0; t < LKP_ / 64; ++t) {
    f32x4 s[4];
    #pragma unroll
    for (int n = 0; n < 4; ++n) {
      #pragma unroll
      for (int r = 0; r < 4; ++r) s[n][r] = 0.f;
      const unsigned short* kp = kbase + (size_t)(t * 64 + n * 16 + lo16) * 64 + hi * 8;
      short8 k0 = *(const short8*)kp;
      short8 k1 = *(const short8*)(kp + 32);
      s[n] = MFMA16(qf0, k0, s[n]);
      s[n] = MFMA16(qf1, k1, s[n]);
    }
    if (t == LKP_ / 64 - 1) {
      #pragma unroll
      for (int n = 0; n < 4; ++n)
        if (t * 64 + n * 16 + lo16 >= LKV_) {
          #pragma unroll
          for (int r = 0; r < 4; ++r) s[n][r] = -1e30f;
        }
    }
    // online softmax (rows live in 16-lane groups)
    float tm[4];
    #pragma unroll
    for (int r = 0; r < 4; ++r)
      tm[r] = fmaxf(fmaxf(s[0][r], s[1][r]), fmaxf(s[2][r], s[3][r]));
    #pragma unroll
    for (int off = 1; off <= 8; off <<= 1)
      #pragma unroll
      for (int r = 0; r < 4; ++r) tm[r] = fmaxf(tm[r], __shfl_xor(tm[r], off));
    float al[4];
    #pragma unroll
    for (int r = 0; r < 4; ++r) {
      float mn = fmaxf(mreg[r], tm[r]);
      al[r] = __expf(mreg[r] - mn);
      mreg[r] = mn;
    }
    f32x4 p[4];
    float ps[4] = {0.f, 0.f, 0.f, 0.f};
    #pragma unroll
    for (int n = 0; n < 4; ++n)
      #pragma unroll
      for (int r = 0; r < 4; ++r) {
        float e = __expf(s[n][r] - mreg[r]);
        p[n][r] = e;
        ps[r] += e;
      }
    #pragma unroll
    for (int off = 1; off <= 8; off <<= 1)
      #pragma unroll
      for (int r = 0; r < 4; ++r) ps[r] += __shfl_xor(ps[r], off);
    #pragma unroll
    for (int r = 0; r < 4; ++r) lsum[r] = lsum[r] * al[r] + ps[r];
    #pragma unroll
    for (int df = 0; df < 4; ++df)
      #pragma unroll
      for (int r = 0; r < 4; ++r) o[df][r] *= al[r];
    // P: D-layout -> LDS -> A-layout (per-wave, no barrier needed)
    #pragma unroll
    for (int n = 0; n < 4; ++n)
      #pragma unroll
      for (int r = 0; r < 4; ++r)
        P[wv][hi * 4 + r][lo16 + 16 * n] = f2bf(p[n][r]);
    short8 pa0 = *(const short8*)&P[wv][lo16][hi * 8];
    short8 pa1 = *(const short8*)&P[wv][lo16][32 + hi * 8];
    #pragma unroll
    for (int df = 0; df < 4; ++df) {
      const unsigned short* vp = vbase + (size_t)(df * 16 + lo16) * LKP_ + t * 64 + hi * 8;
      short8 v0 = *(const short8*)vp;
      short8 v1 = *(const short8*)(vp + 32);
      o[df] = MFMA16(pa0, v0, o[df]);
      o[df] = MFMA16(pa1, v1, o[df]);
    }
  }
  float rinv[4];
  #pragma unroll
  for (int r = 0; r < 4; ++r) rinv[r] = 1.f / lsum[r];
  #pragma unroll
  for (int df = 0; df < 4; ++df)
    #pragma unroll
    for (int r = 0; r < 4; ++r)
      outp[((size_t)b * N_ + qb * 64 + wv * 16 + hi * 4 + r) * C_ + h * 64 + df * 16 + lo16] =
          o[df][r] * rinv[r];
}

extern "C" void kernel_launch(void* const* d_in, const int* in_sizes, int n_in,
                              void* d_out, int out_size, void* d_ws, size_t ws_size,
                              hipStream_t stream)
{
  const float* x      = (const float*)d_in[0];
  const float* ctx    = (const float*)d_in[1];
  const float* mask1  = (const float*)d_in[2];
  const float* mask2  = (const float*)d_in[3];
  const float* q_w    = (const float*)d_in[4];
  const float* q_b    = (const float*)d_in[5];
  const float* kv1_w  = (const float*)d_in[6];
  const float* kv1_b  = (const float*)d_in[7];
  const float* kv2_w  = (const float*)d_in[8];
  const float* kv2_b  = (const float*)d_in[9];
  const float* f1_w   = (const float*)d_in[10];
  const float* f1_b   = (const float*)d_in[11];
  const float* f2_w   = (const float*)d_in[12];
  const float* f2_b   = (const float*)d_in[13];
  const float* lepe_w = (const float*)d_in[14];
  const float* lepe_b = (const float*)d_in[15];
  const float* lcw    = (const float*)d_in[16];
  const float* lcb    = (const float*)d_in[17];
  const float* proj_w = (const float*)d_in[18];
  const float* proj_b = (const float*)d_in[19];
  float* outp = (float*)d_out;

  char* ws = (char*)d_ws;
  float*          bufA  = (float*)(ws);                      // 18,874,368
  float*          bufB  = (float*)(ws + 18874368);           // 18,874,368
  unsigned short* xb    = (unsigned short*)(ws + 37748736);  // 9,437,184 (later Abf)
  unsigned short* Qb    = (unsigned short*)(ws + 47185920);  // 9,437,184
  unsigned short* wb    = (unsigned short*)(ws + 56623104);  // 2,621,440 (5 weights)
  unsigned short* seqb1 = (unsigned short*)(ws + 59244544);  // 2,883,584
  unsigned short* seqb2 = (unsigned short*)(ws + 62128128);  // 2,883,584
  unsigned short* kv1b  = (unsigned short*)(ws + 65011712);  // 2,883,584
  unsigned short* kv2b  = (unsigned short*)(ws + 67895296);  // 2,883,584
  unsigned short* Kb    = (unsigned short*)(ws + 70778880);  // 2,883,584
  unsigned short* Vtb   = (unsigned short*)(ws + 73662464);  // 2,883,584
  int*            idx1  = (int*)(ws + 76546048);             // 36,864
  int*            idx2  = (int*)(ws + 76582912);             // 36,864

  unsigned short* wb_lepe = wb;
  unsigned short* wb_q    = wb + 262144;
  unsigned short* wb_kv1  = wb + 524288;
  unsigned short* wb_kv2  = wb + 786432;
  unsigned short* wb_proj = wb + 1048576;

  dim3 blk(256);
  const int WN = 262144;          // 512*512
  const int XN = B_ * N_ * C_;    // 4,718,592

  // weight + x packs
  pack_bf16<<<dim3(WN / 1024), blk, 0, stream>>>(lepe_w, wb_lepe, WN, 1.f);
  pack_bf16<<<dim3(WN / 1024), blk, 0, stream>>>(q_w,    wb_q,    WN, 1.f);
  pack_bf16<<<dim3(WN / 1024), blk, 0, stream>>>(kv1_w,  wb_kv1,  WN, 1.f);
  pack_bf16<<<dim3(WN / 1024), blk, 0, stream>>>(kv2_w,  wb_kv2,  WN, 1.f);
  pack_bf16<<<dim3(WN / 1024), blk, 0, stream>>>(proj_w, wb_proj, WN, 1.f);
  pack_bf16<<<dim3(XN / 1024), blk, 0, stream>>>(x, xb, XN, 1.f);

  // argsorts (both masks, 8 blocks)
  argsort_kernel<<<dim3(8), dim3(1024), 0, stream>>>(mask1, mask2, idx1, idx2);

  // pooled sequences (bf16, zero-padded to 704 rows per b)
  pool_kernel<<<dim3(B_ * LKP_), blk, 0, stream>>>(ctx, idx1, f1_w, f1_b, f2_w, f2_b, seqb1, 0);
  pool_kernel<<<dim3(B_ * LKP_), blk, 0, stream>>>(ctx, idx2, f1_w, f1_b, f2_w, f2_b, seqb2, 1);

  // kv projections -> bf16
  gemm_bf16<<<dim3(22, 4), blk, 0, stream>>>(seqb1, wb_kv1, kv1_b, kv1b, C_, C_, 1, 1.f);
  gemm_bf16<<<dim3(22, 4), blk, 0, stream>>>(seqb2, wb_kv2, kv2_b, kv2b, C_, C_, 1, 1.f);
  kvpack_k<<<dim3(B_ * 8 * LKP_ * 64 / 256), blk, 0, stream>>>(kv1b, kv2b, Kb);
  kvpack_v<<<dim3(B_ * 8 * LKP_ * 64 / 256), blk, 0, stream>>>(kv1b, kv2b, Vtb);

  // lepe: linear (fp32 out) + depthwise conv
  gemm_bf16<<<dim3(72, 4), blk, 0, stream>>>(xb, wb_lepe, lepe_b, bufA, C_, C_, 0, 1.f);
  dwconv_kernel<<<dim3(XN / 256), blk, 0, stream>>>(bufA, lcw, lcb, bufB);

  // q projection -> bf16 with folded softmax scale (1/8, exact)
  gemm_bf16<<<dim3(72, 4), blk, 0, stream>>>(xb, wb_q, q_b, Qb, C_, C_, 1, 0.125f);

  // fused attention -> fp32 into bufA (lepe-lin already consumed)
  attn_kernel<<<dim3(B_ * NH_ * (N_ / 64)), blk, 0, stream>>>(Qb, Kb, Vtb, bufA);

  // (attn + lepe) -> bf16 (reuse xb; x fully consumed)
  addpack_bf16<<<dim3(XN / 1024), blk, 0, stream>>>(bufA, bufB, xb, XN);

  // final projection -> d_out fp32
  gemm_bf16<<<dim3(72, 4), blk, 0, stream>>>(xb, wb_proj, proj_b, (void*)outp, C_, C_, 0, 1.f);
}

// Round 3
// 279.300 us; speedup vs baseline: 6.8811x; 1.4558x over previous
//
#include <hip/hip_runtime.h>
#include <hip/hip_bf16.h>
#include <math.h>

#define B_    4
#define H_    48
#define W_    48
#define N_    2304
#define C_    512
#define NH_   8
#define HD_   64
#define LKV_  684
#define LKP_  704      // padded kv length (11 * 64)

typedef __attribute__((ext_vector_type(8))) short short8;
typedef __attribute__((ext_vector_type(4))) float f32x4;

#define MFMA16(a, b, c) __builtin_amdgcn_mfma_f32_16x16x32_bf16(a, b, c, 0, 0, 0)

__device__ __forceinline__ unsigned short f2bf(float f) {
  __hip_bfloat16 h = __float2bfloat16(f);
  return *reinterpret_cast<unsigned short*>(&h);
}

// ---------------- fused fp32 -> bf16 pack of 5 weights + x (one launch)
__global__ __launch_bounds__(256) void pack_all(
    const float* __restrict__ lepe_w, const float* __restrict__ q_w,
    const float* __restrict__ kv1_w, const float* __restrict__ kv2_w,
    const float* __restrict__ proj_w, const float* __restrict__ x,
    unsigned short* __restrict__ wb, unsigned short* __restrict__ xb)
{
  int i = (blockIdx.x * 256 + threadIdx.x) * 4;
  const float* s; unsigned short* d; int rel;
  if      (i < 262144)  { s = lepe_w; d = wb;           rel = i; }
  else if (i < 524288)  { s = q_w;    d = wb + 262144;  rel = i - 262144; }
  else if (i < 786432)  { s = kv1_w;  d = wb + 524288;  rel = i - 524288; }
  else if (i < 1048576) { s = kv2_w;  d = wb + 786432;  rel = i - 786432; }
  else if (i < 1310720) { s = proj_w; d = wb + 1048576; rel = i - 1048576; }
  else                  { s = x;      d = xb;           rel = i - 1310720; }
  float4 v = *(const float4*)(s + rel);
  ushort4 o;
  o.x = f2bf(v.x); o.y = f2bf(v.y); o.z = f2bf(v.z); o.w = f2bf(v.w);
  *(ushort4*)(d + rel) = o;
}

// ---------------- bf16 MFMA GEMM (NT): out[m,n] = A[m,:] . Bw[n,:] + bias[n]
__global__ __launch_bounds__(256) void gemm_bf16(
    const unsigned short* __restrict__ A, const unsigned short* __restrict__ Bw,
    const float* __restrict__ bias, void* __restrict__ out,
    int K, int Nn, int out_bf16, float oscale)
{
  __shared__ unsigned short Abuf[128][40];
  __shared__ unsigned short Bbuf[128][40];
  const int tid = threadIdx.x;
  const int l = tid & 63, w = tid >> 6;
  const int wm = w >> 1, wn = w & 1;
  const int lo16 = l & 15, hi = l >> 4;
  const int row0 = blockIdx.x * 128, col0 = blockIdx.y * 128;
  const int srow = tid >> 2, scol = (tid & 3) * 8;

  f32x4 acc[4][4];
  #pragma unroll
  for (int m = 0; m < 4; ++m)
    #pragma unroll
    for (int n = 0; n < 4; ++n)
      #pragma unroll
      for (int r = 0; r < 4; ++r) acc[m][n][r] = 0.f;

  for (int k0 = 0; k0 < K; k0 += 32) {
    uint4 a0 = *(const uint4*)(A + (size_t)(row0 + srow) * K + k0 + scol);
    uint4 a1 = *(const uint4*)(A + (size_t)(row0 + 64 + srow) * K + k0 + scol);
    uint4 b0 = *(const uint4*)(Bw + (size_t)(col0 + srow) * K + k0 + scol);
    uint4 b1 = *(const uint4*)(Bw + (size_t)(col0 + 64 + srow) * K + k0 + scol);
    __syncthreads();
    *(uint4*)&Abuf[srow][scol]      = a0;
    *(uint4*)&Abuf[64 + srow][scol] = a1;
    *(uint4*)&Bbuf[srow][scol]      = b0;
    *(uint4*)&Bbuf[64 + srow][scol] = b1;
    __syncthreads();
    short8 af[4], bf[4];
    #pragma unroll
    for (int m = 0; m < 4; ++m)
      af[m] = *(const short8*)&Abuf[wm * 64 + m * 16 + lo16][hi * 8];
    #pragma unroll
    for (int n = 0; n < 4; ++n)
      bf[n] = *(const short8*)&Bbuf[wn * 64 + n * 16 + lo16][hi * 8];
    #pragma unroll
    for (int m = 0; m < 4; ++m)
      #pragma unroll
      for (int n = 0; n < 4; ++n)
        acc[m][n] = MFMA16(af[m], bf[n], acc[m][n]);
  }

  #pragma unroll
  for (int m = 0; m < 4; ++m) {
    #pragma unroll
    for (int n = 0; n < 4; ++n) {
      int gcol = col0 + wn * 64 + n * 16 + lo16;
      #pragma unroll
      for (int r = 0; r < 4; ++r) {
        int grow = row0 + wm * 64 + m * 16 + hi * 4 + r;
        float v = acc[m][n][r] + bias[gcol];
        if (out_bf16)
          ((unsigned short*)out)[(size_t)grow * Nn + gcol] = f2bf(v * oscale);
        else
          ((float*)out)[(size_t)grow * Nn + gcol] = v;
      }
    }
  }
}

// ---------------- depthwise 3x3 conv, channel-last [B,H,W,C] fp32
__global__ __launch_bounds__(256) void dwconv_kernel(
    const float* __restrict__ lin, const float* __restrict__ cw,
    const float* __restrict__ cb, float* __restrict__ outp)
{
  size_t gid = (size_t)blockIdx.x * blockDim.x + threadIdx.x;
  if (gid >= (size_t)B_ * N_ * C_) return;
  int c = (int)(gid % C_);
  size_t t = gid / C_;
  int wv = (int)(t % W_);
  size_t r = t / W_;
  int hv = (int)(r % H_);
  int b  = (int)(r / H_);
  float acc = cb[c];
  const float* wgt = cw + c * 9;
  #pragma unroll
  for (int dy = 0; dy < 3; ++dy) {
    int hh = hv + dy - 1;
    if (hh < 0 || hh >= H_) continue;
    #pragma unroll
    for (int dx = 0; dx < 3; ++dx) {
      int ww = wv + dx - 1;
      if (ww < 0 || ww >= W_) continue;
      acc += wgt[dy * 3 + dx] * lin[(((size_t)b * H_ + hh) * W_ + ww) * C_ + c];
    }
  }
  outp[gid] = acc;
}

// ---------------- stable argsort via rank counting
// grid: 8 rows (4 mask1 + 4 mask2) x 36 chunks of 64 elements; 4 lanes/element.
__global__ __launch_bounds__(256) void rank_argsort(
    const float* __restrict__ m1, const float* __restrict__ m2,
    int* __restrict__ i1, int* __restrict__ i2)
{
  __shared__ float key[N_];
  const int blk = blockIdx.x;
  const int row = blk / 36, chunk = blk % 36;
  const float* m = (row < 4) ? (m1 + (size_t)row * N_) : (m2 + (size_t)(row - 4) * N_);
  int* out = (row < 4) ? (i1 + (size_t)row * N_) : (i2 + (size_t)(row - 4) * N_);
  for (int i = threadIdx.x; i < N_ / 4; i += 256)
    ((float4*)key)[i] = ((const float4*)m)[i];
  __syncthreads();
  const int e = chunk * 64 + (threadIdx.x >> 2);
  const int sl = threadIdx.x & 3;
  const float ki = key[e];
  int rank = 0;
  #pragma unroll 4
  for (int t = 0; t < N_ / 16; ++t) {
    int jb = sl * 4 + t * 16;
    float4 kv = *(const float4*)&key[jb];
    rank += (kv.x < ki) || (kv.x == ki && jb     < e);
    rank += (kv.y < ki) || (kv.y == ki && jb + 1 < e);
    rank += (kv.z < ki) || (kv.z == ki && jb + 2 < e);
    rank += (kv.w < ki) || (kv.w == ki && jb + 3 < e);
  }
  rank += __shfl_xor(rank, 1);
  rank += __shfl_xor(rank, 2);
  if (sl == 0) out[rank] = e;
}

// ---------------- pooled sequence -> bf16, padded per-b layout [B][704][512]
__global__ __launch_bounds__(256) void pool_kernel(
    const float* __restrict__ ctx, const int* __restrict__ idx,
    const float* __restrict__ f1w, const float* __restrict__ f1b,
    const float* __restrict__ f2w, const float* __restrict__ f2b_,
    unsigned short* __restrict__ seqb, int transposed)
{
  int bl = blockIdx.x;
  int b = bl / LKP_, l = bl % LKP_;
  unsigned short* dst = seqb + ((size_t)b * LKP_ + l) * C_;
  int c0 = threadIdx.x, c1 = threadIdx.x + 256;
  if (l >= LKV_) { dst[c0] = 0; dst[c1] = 0; return; }
  const int* id = idx + (size_t)b * N_;
  int j0, cnt;
  const float* fw; float fb;
  if (l < 12)       { j0 = l * 48;              cnt = 48; fw = f1w; fb = f1b[0]; }
  else if (l < 108) { j0 = 576 + (l - 12) * 12; cnt = 12; fw = f2w; fb = f2b_[0]; }
  else              { j0 = 1728 + (l - 108);    cnt = 1;  fw = nullptr; fb = 0.f; }
  const float* cb = ctx + (size_t)b * N_ * C_;
  float a0 = fb, a1 = fb;
  int r = 0;
  for (; r + 4 <= cnt; r += 4) {
    int4 nv = *(const int4*)(id + j0 + r);
    int n0 = nv.x, n1 = nv.y, n2 = nv.z, n3 = nv.w;
    if (transposed) {
      n0 = (n0 % 48) * 48 + n0 / 48; n1 = (n1 % 48) * 48 + n1 / 48;
      n2 = (n2 % 48) * 48 + n2 / 48; n3 = (n3 % 48) * 48 + n3 / 48;
    }
    const float* s0 = cb + (size_t)n0 * C_;
    const float* s1 = cb + (size_t)n1 * C_;
    const float* s2 = cb + (size_t)n2 * C_;
    const float* s3 = cb + (size_t)n3 * C_;
    float w0 = fw[r], w1 = fw[r+1], w2 = fw[r+2], w3 = fw[r+3];
    a0 += w0 * s0[c0] + w1 * s1[c0] + w2 * s2[c0] + w3 * s3[c0];
    a1 += w0 * s0[c1] + w1 * s1[c1] + w2 * s2[c1] + w3 * s3[c1];
  }
  for (; r < cnt; ++r) {
    int n = id[j0 + r];
    if (transposed) n = (n % 48) * 48 + n / 48;
    const float* src = cb + (size_t)n * C_;
    float wr = fw ? fw[r] : 1.f;
    a0 += wr * src[c0];
    a1 += wr * src[c1];
  }
  dst[c0] = f2bf(a0);
  dst[c1] = f2bf(a1);
}

// ---------------- split kv gemm outputs: K [B,8,704,64] and V^T [B,8,64,704]
__global__ __launch_bounds__(256) void kvpack(
    const unsigned short* __restrict__ kv1, const unsigned short* __restrict__ kv2,
    unsigned short* __restrict__ Kb, unsigned short* __restrict__ Vtb)
{
  const int NKV = B_ * 8 * LKP_ * 64;
  int gid = blockIdx.x * 256 + threadIdx.x;
  if (gid < NKV) {                       // K: ordered (b,h,l,d)
    int d = gid & 63;
    int t = gid >> 6;
    int l = t % LKP_;
    int h = (t / LKP_) & 7;
    int b = t / (LKP_ * 8);
    unsigned short val = 0;
    if (l < LKV_) {
      const unsigned short* src = (h < 4) ? kv1 : kv2;
      val = src[((size_t)(b * LKP_ + l)) * C_ + (h & 3) * 64 + d];
    }
    Kb[gid] = val;
  } else {                               // V^T: ordered (b,h,d,l)
    gid -= NKV;
    int l = gid % LKP_;
    int t = gid / LKP_;
    int d = t & 63;
    int h = (t >> 6) & 7;
    int b = t >> 9;
    unsigned short val = 0;
    if (l < LKV_) {
      const unsigned short* src = (h < 4) ? kv1 : kv2;
      val = src[((size_t)(b * LKP_ + l)) * C_ + 256 + (h & 3) * 64 + d];
    }
    Vtb[gid] = val;
  }
}

// ---------------- fused flash attention, bf16 MFMA; epilogue adds lepe, packs bf16
__global__ __launch_bounds__(256) void attn_kernel(
    const unsigned short* __restrict__ Qb, const unsigned short* __restrict__ Kb,
    const unsigned short* __restrict__ Vtb, const float* __restrict__ lepe,
    unsigned short* __restrict__ outb)
{
  __shared__ unsigned short P[4][16][72];
  const int tid = threadIdx.x, l = tid & 63, wv = tid >> 6;
  const int lo16 = l & 15, hi = l >> 4;
  const int blk = blockIdx.x;
  const int qb = blk % (N_ / 64);
  const int bh = blk / (N_ / 64);
  const int h = bh & 7, b = bh >> 3;

  const int qrow = qb * 64 + wv * 16 + lo16;
  const unsigned short* qptr = Qb + ((size_t)b * N_ + qrow) * C_ + h * 64;
  short8 qf0 = *(const short8*)(qptr + hi * 8);
  short8 qf1 = *(const short8*)(qptr + 32 + hi * 8);

  const unsigned short* kbase = Kb + (size_t)bh * LKP_ * 64;
  const unsigned short* vbase = Vtb + (size_t)bh * 64 * LKP_;

  float mreg[4], lsum[4];
  f32x4 o[4];
  #pragma unroll
  for (int r = 0; r < 4; ++r) { mreg[r] = -INFINITY; lsum[r] = 0.f; }
  #pragma unroll
  for (int df = 0; df < 4; ++df)
    #pragma unroll
    for (int r = 0; r < 4; ++r) o[df][r] = 0.f;

  for (int t = 0; t < LKP_ / 64; ++t) {
    f32x4 s[4];
    #pragma unroll
    for (int n = 0; n < 4; ++n) {
      #pragma unroll
      for (int r = 0; r < 4; ++r) s[n][r] = 0.f;
      const unsigned short* kp = kbase + (size_t)(t * 64 + n * 16 + lo16) * 64 + hi * 8;
      short8 k0 = *(const short8*)kp;
      short8 k1 = *(const short8*)(kp + 32);
      s[n] = MFMA16(qf0, k0, s[n]);
      s[n] = MFMA16(qf1, k1, s[n]);
    }
    if (t == LKP_ / 64 - 1) {
      #pragma unroll
      for (int n = 0; n < 4; ++n)
        if (t * 64 + n * 16 + lo16 >= LKV_) {
          #pragma unroll
          for (int r = 0; r < 4; ++r) s[n][r] = -1e30f;
        }
    }
    float tm[4];
    #pragma unroll
    for (int r = 0; r < 4; ++r)
      tm[r] = fmaxf(fmaxf(s[0][r], s[1][r]), fmaxf(s[2][r], s[3][r]));
    #pragma unroll
    for (int off = 1; off <= 8; off <<= 1)
      #pragma unroll
      for (int r = 0; r < 4; ++r) tm[r] = fmaxf(tm[r], __shfl_xor(tm[r], off));
    float al[4];
    #pragma unroll
    for (int r = 0; r < 4; ++r) {
      float mn = fmaxf(mreg[r], tm[r]);
      al[r] = __expf(mreg[r] - mn);
      mreg[r] = mn;
    }
    f32x4 p[4];
    float ps[4] = {0.f, 0.f, 0.f, 0.f};
    #pragma unroll
    for (int n = 0; n < 4; ++n)
      #pragma unroll
      for (int r = 0; r < 4; ++r) {
        float e = __expf(s[n][r] - mreg[r]);
        p[n][r] = e;
        ps[r] += e;
      }
    #pragma unroll
    for (int off = 1; off <= 8; off <<= 1)
      #pragma unroll
      for (int r = 0; r < 4; ++r) ps[r] += __shfl_xor(ps[r], off);
    #pragma unroll
    for (int r = 0; r < 4; ++r) lsum[r] = lsum[r] * al[r] + ps[r];
    #pragma unroll
    for (int df = 0; df < 4; ++df)
      #pragma unroll
      for (int r = 0; r < 4; ++r) o[df][r] *= al[r];
    #pragma unroll
    for (int n = 0; n < 4; ++n)
      #pragma unroll
      for (int r = 0; r < 4; ++r)
        P[wv][hi * 4 + r][lo16 + 16 * n] = f2bf(p[n][r]);
    short8 pa0 = *(const short8*)&P[wv][lo16][hi * 8];
    short8 pa1 = *(const short8*)&P[wv][lo16][32 + hi * 8];
    #pragma unroll
    for (int df = 0; df < 4; ++df) {
      const unsigned short* vp = vbase + (size_t)(df * 16 + lo16) * LKP_ + t * 64 + hi * 8;
      short8 v0 = *(const short8*)vp;
      short8 v1 = *(const short8*)(vp + 32);
      o[df] = MFMA16(pa0, v0, o[df]);
      o[df] = MFMA16(pa1, v1, o[df]);
    }
  }
  float rinv[4];
  #pragma unroll
  for (int r = 0; r < 4; ++r) rinv[r] = 1.f / lsum[r];
  #pragma unroll
  for (int df = 0; df < 4; ++df)
    #pragma unroll
    for (int r = 0; r < 4; ++r) {
      size_t off = ((size_t)b * N_ + qb * 64 + wv * 16 + hi * 4 + r) * C_ + h * 64 + df * 16 + lo16;
      outb[off] = f2bf(o[df][r] * rinv[r] + lepe[off]);
    }
}

extern "C" void kernel_launch(void* const* d_in, const int* in_sizes, int n_in,
                              void* d_out, int out_size, void* d_ws, size_t ws_size,
                              hipStream_t stream)
{
  const float* x      = (const float*)d_in[0];
  const float* ctx    = (const float*)d_in[1];
  const float* mask1  = (const float*)d_in[2];
  const float* mask2  = (const float*)d_in[3];
  const float* q_w    = (const float*)d_in[4];
  const float* q_b    = (const float*)d_in[5];
  const float* kv1_w  = (const float*)d_in[6];
  const float* kv1_b  = (const float*)d_in[7];
  const float* kv2_w  = (const float*)d_in[8];
  const float* kv2_b  = (const float*)d_in[9];
  const float* f1_w   = (const float*)d_in[10];
  const float* f1_b   = (const float*)d_in[11];
  const float* f2_w   = (const float*)d_in[12];
  const float* f2_b   = (const float*)d_in[13];
  const float* lepe_w = (const float*)d_in[14];
  const float* lepe_b = (const float*)d_in[15];
  const float* lcw    = (const float*)d_in[16];
  const float* lcb    = (const float*)d_in[17];
  const float* proj_w = (const float*)d_in[18];
  const float* proj_b = (const float*)d_in[19];
  float* outp = (float*)d_out;

  char* ws = (char*)d_ws;
  float*          bufA  = (float*)(ws);                      // lepe-lin fp32
  float*          bufB  = (float*)(ws + 18874368);           // lepe fp32
  unsigned short* xb    = (unsigned short*)(ws + 37748736);  // x bf16, later attn+lepe bf16
  unsigned short* Qb    = (unsigned short*)(ws + 47185920);
  unsigned short* wb    = (unsigned short*)(ws + 56623104);
  unsigned short* seqb1 = (unsigned short*)(ws + 59244544);
  unsigned short* seqb2 = (unsigned short*)(ws + 62128128);
  unsigned short* kv1b  = (unsigned short*)(ws + 65011712);
  unsigned short* kv2b  = (unsigned short*)(ws + 67895296);
  unsigned short* Kb    = (unsigned short*)(ws + 70778880);
  unsigned short* Vtb   = (unsigned short*)(ws + 73662464);
  int*            idx1  = (int*)(ws + 76546048);
  int*            idx2  = (int*)(ws + 76582912);

  unsigned short* wb_lepe = wb;
  unsigned short* wb_q    = wb + 262144;
  unsigned short* wb_kv1  = wb + 524288;
  unsigned short* wb_kv2  = wb + 786432;
  unsigned short* wb_proj = wb + 1048576;

  dim3 blk(256);
  const int XN = B_ * N_ * C_;                 // 4,718,592
  const int PACKQ = (1310720 + XN) / 4 / 256;  // 5888 blocks

  pack_all<<<dim3(PACKQ), blk, 0, stream>>>(lepe_w, q_w, kv1_w, kv2_w, proj_w, x, wb, xb);
  rank_argsort<<<dim3(288), blk, 0, stream>>>(mask1, mask2, idx1, idx2);

  pool_kernel<<<dim3(B_ * LKP_), blk, 0, stream>>>(ctx, idx1, f1_w, f1_b, f2_w, f2_b, seqb1, 0);
  pool_kernel<<<dim3(B_ * LKP_), blk, 0, stream>>>(ctx, idx2, f1_w, f1_b, f2_w, f2_b, seqb2, 1);

  gemm_bf16<<<dim3(22, 4), blk, 0, stream>>>(seqb1, wb_kv1, kv1_b, kv1b, C_, C_, 1, 1.f);
  gemm_bf16<<<dim3(22, 4), blk, 0, stream>>>(seqb2, wb_kv2, kv2_b, kv2b, C_, C_, 1, 1.f);
  kvpack<<<dim3(2 * B_ * 8 * LKP_ * 64 / 256), blk, 0, stream>>>(kv1b, kv2b, Kb, Vtb);

  gemm_bf16<<<dim3(72, 4), blk, 0, stream>>>(xb, wb_lepe, lepe_b, bufA, C_, C_, 0, 1.f);
  dwconv_kernel<<<dim3(XN / 256), blk, 0, stream>>>(bufA, lcw, lcb, bufB);

  gemm_bf16<<<dim3(72, 4), blk, 0, stream>>>(xb, wb_q, q_b, Qb, C_, C_, 1, 0.125f);

  // attention + (+lepe, ->bf16) epilogue, overwrites xb
  attn_kernel<<<dim3(B_ * NH_ * (N_ / 64)), blk, 0, stream>>>(Qb, Kb, Vtb, bufB, xb);

  gemm_bf16<<<dim3(72, 4), blk, 0, stream>>>(xb, wb_proj, proj_b, (void*)outp, C_, C_, 0, 1.f);
}

// Round 4
// 263.286 us; speedup vs baseline: 7.2997x; 1.0608x over previous
//
#include <hip/hip_runtime.h>
#include <hip/hip_bf16.h>
#include <math.h>

#define B_    4
#define H_    48
#define W_    48
#define N_    2304
#define C_    512
#define NH_   8
#define HD_   64
#define LKV_  684
#define LKP_  704      // padded kv length (11 * 64)

typedef __attribute__((ext_vector_type(8))) short short8;
typedef __attribute__((ext_vector_type(4))) float f32x4;

#define MFMA16(a, b, c) __builtin_amdgcn_mfma_f32_16x16x32_bf16(a, b, c, 0, 0, 0)

__device__ __forceinline__ unsigned short f2bf(float f) {
  __hip_bfloat16 h = __float2bfloat16(f);
  return *reinterpret_cast<unsigned short*>(&h);
}

// ---------------- fused fp32 -> bf16 pack of 5 weights + x (one launch)
__global__ __launch_bounds__(256) void pack_all(
    const float* __restrict__ lepe_w, const float* __restrict__ q_w,
    const float* __restrict__ kv1_w, const float* __restrict__ kv2_w,
    const float* __restrict__ proj_w, const float* __restrict__ x,
    unsigned short* __restrict__ wb, unsigned short* __restrict__ xb)
{
  int i = (blockIdx.x * 256 + threadIdx.x) * 4;
  const float* s; unsigned short* d; int rel;
  if      (i < 262144)  { s = lepe_w; d = wb;           rel = i; }
  else if (i < 524288)  { s = q_w;    d = wb + 262144;  rel = i - 262144; }
  else if (i < 786432)  { s = kv1_w;  d = wb + 524288;  rel = i - 524288; }
  else if (i < 1048576) { s = kv2_w;  d = wb + 786432;  rel = i - 786432; }
  else if (i < 1310720) { s = proj_w; d = wb + 1048576; rel = i - 1048576; }
  else                  { s = x;      d = xb;           rel = i - 1310720; }
  float4 v = *(const float4*)(s + rel);
  ushort4 o;
  o.x = f2bf(v.x); o.y = f2bf(v.y); o.z = f2bf(v.z); o.w = f2bf(v.w);
  *(ushort4*)(d + rel) = o;
}

// ---------------- paired bf16 MFMA GEMM (NT), blockIdx.z selects config
struct GPair {
  const unsigned short *A0, *A1, *B0, *B1;
  const float *bias0, *bias1;
  void *out0, *out1;
  int bf0, bf1;
  float sc0, sc1;
};

__global__ __launch_bounds__(256) void gemm_bf16(GPair p, int K, int Nn)
{
  const unsigned short* A  = blockIdx.z ? p.A1 : p.A0;
  const unsigned short* Bw = blockIdx.z ? p.B1 : p.B0;
  const float* bias        = blockIdx.z ? p.bias1 : p.bias0;
  void* out                = blockIdx.z ? p.out1 : p.out0;
  const int out_bf16       = blockIdx.z ? p.bf1 : p.bf0;
  const float oscale       = blockIdx.z ? p.sc1 : p.sc0;

  __shared__ unsigned short Abuf[128][40];
  __shared__ unsigned short Bbuf[128][40];
  const int tid = threadIdx.x;
  const int l = tid & 63, w = tid >> 6;
  const int wm = w >> 1, wn = w & 1;
  const int lo16 = l & 15, hi = l >> 4;
  const int row0 = blockIdx.x * 128, col0 = blockIdx.y * 128;
  const int srow = tid >> 2, scol = (tid & 3) * 8;

  f32x4 acc[4][4];
  #pragma unroll
  for (int m = 0; m < 4; ++m)
    #pragma unroll
    for (int n = 0; n < 4; ++n)
      #pragma unroll
      for (int r = 0; r < 4; ++r) acc[m][n][r] = 0.f;

  for (int k0 = 0; k0 < K; k0 += 32) {
    uint4 a0 = *(const uint4*)(A + (size_t)(row0 + srow) * K + k0 + scol);
    uint4 a1 = *(const uint4*)(A + (size_t)(row0 + 64 + srow) * K + k0 + scol);
    uint4 b0 = *(const uint4*)(Bw + (size_t)(col0 + srow) * K + k0 + scol);
    uint4 b1 = *(const uint4*)(Bw + (size_t)(col0 + 64 + srow) * K + k0 + scol);
    __syncthreads();
    *(uint4*)&Abuf[srow][scol]      = a0;
    *(uint4*)&Abuf[64 + srow][scol] = a1;
    *(uint4*)&Bbuf[srow][scol]      = b0;
    *(uint4*)&Bbuf[64 + srow][scol] = b1;
    __syncthreads();
    short8 af[4], bf[4];
    #pragma unroll
    for (int m = 0; m < 4; ++m)
      af[m] = *(const short8*)&Abuf[wm * 64 + m * 16 + lo16][hi * 8];
    #pragma unroll
    for (int n = 0; n < 4; ++n)
      bf[n] = *(const short8*)&Bbuf[wn * 64 + n * 16 + lo16][hi * 8];
    #pragma unroll
    for (int m = 0; m < 4; ++m)
      #pragma unroll
      for (int n = 0; n < 4; ++n)
        acc[m][n] = MFMA16(af[m], bf[n], acc[m][n]);
  }

  #pragma unroll
  for (int m = 0; m < 4; ++m) {
    #pragma unroll
    for (int n = 0; n < 4; ++n) {
      int gcol = col0 + wn * 64 + n * 16 + lo16;
      #pragma unroll
      for (int r = 0; r < 4; ++r) {
        int grow = row0 + wm * 64 + m * 16 + hi * 4 + r;
        float v = acc[m][n][r] + bias[gcol];
        if (out_bf16)
          ((unsigned short*)out)[(size_t)grow * Nn + gcol] = f2bf(v * oscale);
        else
          ((float*)out)[(size_t)grow * Nn + gcol] = v;
      }
    }
  }
}

// ---------------- depthwise 3x3 conv, channel-last [B,H,W,C] fp32
__global__ __launch_bounds__(256) void dwconv_kernel(
    const float* __restrict__ lin, const float* __restrict__ cw,
    const float* __restrict__ cb, float* __restrict__ outp)
{
  size_t gid = (size_t)blockIdx.x * blockDim.x + threadIdx.x;
  if (gid >= (size_t)B_ * N_ * C_) return;
  int c = (int)(gid % C_);
  size_t t = gid / C_;
  int wv = (int)(t % W_);
  size_t r = t / W_;
  int hv = (int)(r % H_);
  int b  = (int)(r / H_);
  float acc = cb[c];
  const float* wgt = cw + c * 9;
  #pragma unroll
  for (int dy = 0; dy < 3; ++dy) {
    int hh = hv + dy - 1;
    if (hh < 0 || hh >= H_) continue;
    #pragma unroll
    for (int dx = 0; dx < 3; ++dx) {
      int ww = wv + dx - 1;
      if (ww < 0 || ww >= W_) continue;
      acc += wgt[dy * 3 + dx] * lin[(((size_t)b * H_ + hh) * W_ + ww) * C_ + c];
    }
  }
  outp[gid] = acc;
}

// ---------------- stable argsort via rank counting
__global__ __launch_bounds__(256) void rank_argsort(
    const float* __restrict__ m1, const float* __restrict__ m2,
    int* __restrict__ i1, int* __restrict__ i2)
{
  __shared__ float key[N_];
  const int blk = blockIdx.x;
  const int row = blk / 36, chunk = blk % 36;
  const float* m = (row < 4) ? (m1 + (size_t)row * N_) : (m2 + (size_t)(row - 4) * N_);
  int* out = (row < 4) ? (i1 + (size_t)row * N_) : (i2 + (size_t)(row - 4) * N_);
  for (int i = threadIdx.x; i < N_ / 4; i += 256)
    ((float4*)key)[i] = ((const float4*)m)[i];
  __syncthreads();
  const int e = chunk * 64 + (threadIdx.x >> 2);
  const int sl = threadIdx.x & 3;
  const float ki = key[e];
  int rank = 0;
  #pragma unroll 4
  for (int t = 0; t < N_ / 16; ++t) {
    int jb = sl * 4 + t * 16;
    float4 kv = *(const float4*)&key[jb];
    rank += (kv.x < ki) || (kv.x == ki && jb     < e);
    rank += (kv.y < ki) || (kv.y == ki && jb + 1 < e);
    rank += (kv.z < ki) || (kv.z == ki && jb + 2 < e);
    rank += (kv.w < ki) || (kv.w == ki && jb + 3 < e);
  }
  rank += __shfl_xor(rank, 1);
  rank += __shfl_xor(rank, 2);
  if (sl == 0) out[rank] = e;
}

// ---------------- pooled sequences (both orderings in one launch)
__global__ __launch_bounds__(256) void pool_kernel(
    const float* __restrict__ ctx,
    const int* __restrict__ idx1, const int* __restrict__ idx2,
    const float* __restrict__ f1w, const float* __restrict__ f1b,
    const float* __restrict__ f2w, const float* __restrict__ f2b_,
    unsigned short* __restrict__ seqb1, unsigned short* __restrict__ seqb2)
{
  int bl = blockIdx.x;
  const int transposed = bl >= B_ * LKP_;
  if (transposed) bl -= B_ * LKP_;
  const int* idx = transposed ? idx2 : idx1;
  unsigned short* seqb = transposed ? seqb2 : seqb1;
  int b = bl / LKP_, l = bl % LKP_;
  unsigned short* dst = seqb + ((size_t)b * LKP_ + l) * C_;
  int c0 = threadIdx.x, c1 = threadIdx.x + 256;
  if (l >= LKV_) { dst[c0] = 0; dst[c1] = 0; return; }
  const int* id = idx + (size_t)b * N_;
  int j0, cnt;
  const float* fw; float fb;
  if (l < 12)       { j0 = l * 48;              cnt = 48; fw = f1w; fb = f1b[0]; }
  else if (l < 108) { j0 = 576 + (l - 12) * 12; cnt = 12; fw = f2w; fb = f2b_[0]; }
  else              { j0 = 1728 + (l - 108);    cnt = 1;  fw = nullptr; fb = 0.f; }
  const float* cb = ctx + (size_t)b * N_ * C_;
  float a0 = fb, a1 = fb;
  int r = 0;
  for (; r + 4 <= cnt; r += 4) {
    int4 nv = *(const int4*)(id + j0 + r);
    int n0 = nv.x, n1 = nv.y, n2 = nv.z, n3 = nv.w;
    if (transposed) {
      n0 = (n0 % 48) * 48 + n0 / 48; n1 = (n1 % 48) * 48 + n1 / 48;
      n2 = (n2 % 48) * 48 + n2 / 48; n3 = (n3 % 48) * 48 + n3 / 48;
    }
    const float* s0 = cb + (size_t)n0 * C_;
    const float* s1 = cb + (size_t)n1 * C_;
    const float* s2 = cb + (size_t)n2 * C_;
    const float* s3 = cb + (size_t)n3 * C_;
    float w0 = fw[r], w1 = fw[r+1], w2 = fw[r+2], w3 = fw[r+3];
    a0 += w0 * s0[c0] + w1 * s1[c0] + w2 * s2[c0] + w3 * s3[c0];
    a1 += w0 * s0[c1] + w1 * s1[c1] + w2 * s2[c1] + w3 * s3[c1];
  }
  for (; r < cnt; ++r) {
    int n = id[j0 + r];
    if (transposed) n = (n % 48) * 48 + n / 48;
    const float* src = cb + (size_t)n * C_;
    float wr = fw ? fw[r] : 1.f;
    a0 += wr * src[c0];
    a1 += wr * src[c1];
  }
  dst[c0] = f2bf(a0);
  dst[c1] = f2bf(a1);
}

// ---------------- split kv gemm outputs: K [B,8,704,64] and V^T [B,8,64,704]
__global__ __launch_bounds__(256) void kvpack(
    const unsigned short* __restrict__ kv1, const unsigned short* __restrict__ kv2,
    unsigned short* __restrict__ Kb, unsigned short* __restrict__ Vtb)
{
  const int NKV = B_ * 8 * LKP_ * 64;
  int gid = blockIdx.x * 256 + threadIdx.x;
  if (gid < NKV) {                       // K: ordered (b,h,l,d)
    int d = gid & 63;
    int t = gid >> 6;
    int l = t % LKP_;
    int h = (t / LKP_) & 7;
    int b = t / (LKP_ * 8);
    unsigned short val = 0;
    if (l < LKV_) {
      const unsigned short* src = (h < 4) ? kv1 : kv2;
      val = src[((size_t)(b * LKP_ + l)) * C_ + (h & 3) * 64 + d];
    }
    Kb[gid] = val;
  } else {                               // V^T: ordered (b,h,d,l)
    gid -= NKV;
    int l = gid % LKP_;
    int t = gid / LKP_;
    int d = t & 63;
    int h = (t >> 6) & 7;
    int b = t >> 9;
    unsigned short val = 0;
    if (l < LKV_) {
      const unsigned short* src = (h < 4) ? kv1 : kv2;
      val = src[((size_t)(b * LKP_ + l)) * C_ + 256 + (h & 3) * 64 + d];
    }
    Vtb[gid] = val;
  }
}

// ---------------- fused flash attention, bf16 MFMA, software-pipelined K/V
__global__ __launch_bounds__(256) void attn_kernel(
    const unsigned short* __restrict__ Qb, const unsigned short* __restrict__ Kb,
    const unsigned short* __restrict__ Vtb, const float* __restrict__ lepe,
    unsigned short* __restrict__ outb)
{
  __shared__ unsigned short P[4][16][72];
  const int tid = threadIdx.x, l = tid & 63, wv = tid >> 6;
  const int lo16 = l & 15, hi = l >> 4;
  const int blk = blockIdx.x;
  const int qb = blk % (N_ / 64);
  const int bh = blk / (N_ / 64);
  const int h = bh & 7, b = bh >> 3;

  const int qrow = qb * 64 + wv * 16 + lo16;
  const unsigned short* qptr = Qb + ((size_t)b * N_ + qrow) * C_ + h * 64;
  short8 qf0 = *(const short8*)(qptr + hi * 8);
  short8 qf1 = *(const short8*)(qptr + 32 + hi * 8);

  // lane offsets folded into bases
  const unsigned short* kbase = Kb + (size_t)bh * LKP_ * 64 + (size_t)lo16 * 64 + hi * 8;
  const unsigned short* vbase = Vtb + (size_t)bh * 64 * LKP_ + (size_t)lo16 * LKP_ + hi * 8;

  float mreg[4], lsum[4];
  f32x4 o[4];
  #pragma unroll
  for (int r = 0; r < 4; ++r) { mreg[r] = -INFINITY; lsum[r] = 0.f; }
  #pragma unroll
  for (int df = 0; df < 4; ++df)
    #pragma unroll
    for (int r = 0; r < 4; ++r) o[df][r] = 0.f;

  // prologue: K tile 0 into current regs
  short8 ka0[4], ka1[4], kn0[4], kn1[4];
  #pragma unroll
  for (int n = 0; n < 4; ++n) {
    const unsigned short* kp = kbase + n * 16 * 64;
    ka0[n] = *(const short8*)kp;
    ka1[n] = *(const short8*)(kp + 32);
  }

  for (int t = 0; t < LKP_ / 64; ++t) {
    // issue V[t] loads first (independent of QK^T) — latency hides under
    // QK MFMA + softmax + P LDS roundtrip
    short8 vf0[4], vf1[4];
    #pragma unroll
    for (int df = 0; df < 4; ++df) {
      const unsigned short* vp = vbase + (size_t)df * 16 * LKP_ + t * 64;
      vf0[df] = *(const short8*)vp;
      vf1[df] = *(const short8*)(vp + 32);
    }
    // prefetch K[t+1] (consumed next iteration)
    if (t < LKP_ / 64 - 1) {
      #pragma unroll
      for (int n = 0; n < 4; ++n) {
        const unsigned short* kp = kbase + (t + 1) * 64 * 64 + n * 16 * 64;
        kn0[n] = *(const short8*)kp;
        kn1[n] = *(const short8*)(kp + 32);
      }
    }
    // QK^T on current (already-resident) K
    f32x4 s[4];
    #pragma unroll
    for (int n = 0; n < 4; ++n) {
      #pragma unroll
      for (int r = 0; r < 4; ++r) s[n][r] = 0.f;
      s[n] = MFMA16(qf0, ka0[n], s[n]);
      s[n] = MFMA16(qf1, ka1[n], s[n]);
    }
    if (t == LKP_ / 64 - 1) {
      #pragma unroll
      for (int n = 0; n < 4; ++n)
        if (t * 64 + n * 16 + lo16 >= LKV_) {
          #pragma unroll
          for (int r = 0; r < 4; ++r) s[n][r] = -1e30f;
        }
    }
    // online softmax (rows in 16-lane groups)
    float tm[4];
    #pragma unroll
    for (int r = 0; r < 4; ++r)
      tm[r] = fmaxf(fmaxf(s[0][r], s[1][r]), fmaxf(s[2][r], s[3][r]));
    #pragma unroll
    for (int off = 1; off <= 8; off <<= 1)
      #pragma unroll
      for (int r = 0; r < 4; ++r) tm[r] = fmaxf(tm[r], __shfl_xor(tm[r], off));
    float al[4];
    #pragma unroll
    for (int r = 0; r < 4; ++r) {
      float mn = fmaxf(mreg[r], tm[r]);
      al[r] = __expf(mreg[r] - mn);
      mreg[r] = mn;
    }
    float ps[4] = {0.f, 0.f, 0.f, 0.f};
    #pragma unroll
    for (int n = 0; n < 4; ++n)
      #pragma unroll
      for (int r = 0; r < 4; ++r) {
        float e = __expf(s[n][r] - mreg[r]);
        ps[r] += e;
        P[wv][hi * 4 + r][lo16 + 16 * n] = f2bf(e);   // fused pack->LDS
      }
    #pragma unroll
    for (int off = 1; off <= 8; off <<= 1)
      #pragma unroll
      for (int r = 0; r < 4; ++r) ps[r] += __shfl_xor(ps[r], off);
    #pragma unroll
    for (int r = 0; r < 4; ++r) lsum[r] = lsum[r] * al[r] + ps[r];
    #pragma unroll
    for (int df = 0; df < 4; ++df)
      #pragma unroll
      for (int r = 0; r < 4; ++r) o[df][r] *= al[r];
    short8 pa0 = *(const short8*)&P[wv][lo16][hi * 8];
    short8 pa1 = *(const short8*)&P[wv][lo16][32 + hi * 8];
    #pragma unroll
    for (int df = 0; df < 4; ++df) {
      o[df] = MFMA16(pa0, vf0[df], o[df]);
      o[df] = MFMA16(pa1, vf1[df], o[df]);
    }
    // rotate K buffers
    #pragma unroll
    for (int n = 0; n < 4; ++n) { ka0[n] = kn0[n]; ka1[n] = kn1[n]; }
  }

  float rinv[4];
  #pragma unroll
  for (int r = 0; r < 4; ++r) rinv[r] = 1.f / lsum[r];
  #pragma unroll
  for (int df = 0; df < 4; ++df)
    #pragma unroll
    for (int r = 0; r < 4; ++r) {
      size_t off = ((size_t)b * N_ + qb * 64 + wv * 16 + hi * 4 + r) * C_ + h * 64 + df * 16 + lo16;
      outb[off] = f2bf(o[df][r] * rinv[r] + lepe[off]);
    }
}

extern "C" void kernel_launch(void* const* d_in, const int* in_sizes, int n_in,
                              void* d_out, int out_size, void* d_ws, size_t ws_size,
                              hipStream_t stream)
{
  const float* x      = (const float*)d_in[0];
  const float* ctx    = (const float*)d_in[1];
  const float* mask1  = (const float*)d_in[2];
  const float* mask2  = (const float*)d_in[3];
  const float* q_w    = (const float*)d_in[4];
  const float* q_b    = (const float*)d_in[5];
  const float* kv1_w  = (const float*)d_in[6];
  const float* kv1_b  = (const float*)d_in[7];
  const float* kv2_w  = (const float*)d_in[8];
  const float* kv2_b  = (const float*)d_in[9];
  const float* f1_w   = (const float*)d_in[10];
  const float* f1_b   = (const float*)d_in[11];
  const float* f2_w   = (const float*)d_in[12];
  const float* f2_b   = (const float*)d_in[13];
  const float* lepe_w = (const float*)d_in[14];
  const float* lepe_b = (const float*)d_in[15];
  const float* lcw    = (const float*)d_in[16];
  const float* lcb    = (const float*)d_in[17];
  const float* proj_w = (const float*)d_in[18];
  const float* proj_b = (const float*)d_in[19];
  float* outp = (float*)d_out;

  char* ws = (char*)d_ws;
  float*          bufA  = (float*)(ws);                      // lepe-lin fp32
  float*          bufB  = (float*)(ws + 18874368);           // lepe fp32
  unsigned short* xb    = (unsigned short*)(ws + 37748736);  // x bf16 -> attn+lepe bf16
  unsigned short* Qb    = (unsigned short*)(ws + 47185920);
  unsigned short* wb    = (unsigned short*)(ws + 56623104);
  unsigned short* seqb1 = (unsigned short*)(ws + 59244544);
  unsigned short* seqb2 = (unsigned short*)(ws + 62128128);
  unsigned short* kv1b  = (unsigned short*)(ws + 65011712);
  unsigned short* kv2b  = (unsigned short*)(ws + 67895296);
  unsigned short* Kb    = (unsigned short*)(ws + 70778880);
  unsigned short* Vtb   = (unsigned short*)(ws + 73662464);
  int*            idx1  = (int*)(ws + 76546048);
  int*            idx2  = (int*)(ws + 76582912);

  unsigned short* wb_lepe = wb;
  unsigned short* wb_q    = wb + 262144;
  unsigned short* wb_kv1  = wb + 524288;
  unsigned short* wb_kv2  = wb + 786432;
  unsigned short* wb_proj = wb + 1048576;

  dim3 blk(256);
  const int XN = B_ * N_ * C_;                 // 4,718,592
  const int PACKQ = (1310720 + XN) / 4 / 256;  // 5888 blocks

  pack_all<<<dim3(PACKQ), blk, 0, stream>>>(lepe_w, q_w, kv1_w, kv2_w, proj_w, x, wb, xb);
  rank_argsort<<<dim3(288), blk, 0, stream>>>(mask1, mask2, idx1, idx2);

  pool_kernel<<<dim3(2 * B_ * LKP_), blk, 0, stream>>>(
      ctx, idx1, idx2, f1_w, f1_b, f2_w, f2_b, seqb1, seqb2);

  // kv1 + kv2 projections in one launch
  {
    GPair p = { seqb1, seqb2, wb_kv1, wb_kv2, kv1_b, kv2_b,
                (void*)kv1b, (void*)kv2b, 1, 1, 1.f, 1.f };
    gemm_bf16<<<dim3(22, 4, 2), blk, 0, stream>>>(p, C_, C_);
  }
  kvpack<<<dim3(2 * B_ * 8 * LKP_ * 64 / 256), blk, 0, stream>>>(kv1b, kv2b, Kb, Vtb);

  // lepe linear (fp32 out) + q projection (bf16, folded 1/8 scale) in one launch
  {
    GPair p = { xb, xb, wb_lepe, wb_q, lepe_b, q_b,
                (void*)bufA, (void*)Qb, 0, 1, 1.f, 0.125f };
    gemm_bf16<<<dim3(72, 4, 2), blk, 0, stream>>>(p, C_, C_);
  }
  dwconv_kernel<<<dim3(XN / 256), blk, 0, stream>>>(bufA, lcw, lcb, bufB);

  // pipelined attention + (+lepe, ->bf16) epilogue, overwrites xb
  attn_kernel<<<dim3(B_ * NH_ * (N_ / 64)), blk, 0, stream>>>(Qb, Kb, Vtb, bufB, xb);

  // final projection -> d_out fp32
  {
    GPair p = { xb, xb, wb_proj, wb_proj, proj_b, proj_b,
                (void*)outp, (void*)outp, 0, 0, 1.f, 1.f };
    gemm_bf16<<<dim3(72, 4, 1), blk, 0, stream>>>(p, C_, C_);
  }
}

// Round 5
// 198.935 us; speedup vs baseline: 9.6609x; 1.3235x over previous
//
#include <hip/hip_runtime.h>
#include <hip/hip_bf16.h>
#include <math.h>

#define B_    4
#define H_    48
#define W_    48
#define N_    2304
#define C_    512
#define NH_   8
#define HD_   64
#define LKV_  684
#define LKP_  704      // padded kv length (11 * 64)

typedef __attribute__((ext_vector_type(8))) short short8;
typedef __attribute__((ext_vector_type(4))) float f32x4;

#define MFMA16(a, b, c) __builtin_amdgcn_mfma_f32_16x16x32_bf16(a, b, c, 0, 0, 0)

__device__ __forceinline__ unsigned short f2bf(float f) {
  __hip_bfloat16 h = __float2bfloat16(f);
  return *reinterpret_cast<unsigned short*>(&h);
}

// ---------------- fused fp32 -> bf16 pack of 5 weights + x (one launch)
__global__ __launch_bounds__(256) void pack_all(
    const float* __restrict__ lepe_w, const float* __restrict__ q_w,
    const float* __restrict__ kv1_w, const float* __restrict__ kv2_w,
    const float* __restrict__ proj_w, const float* __restrict__ x,
    unsigned short* __restrict__ wb, unsigned short* __restrict__ xb)
{
  int i = (blockIdx.x * 256 + threadIdx.x) * 4;
  const float* s; unsigned short* d; int rel;
  if      (i < 262144)  { s = lepe_w; d = wb;           rel = i; }
  else if (i < 524288)  { s = q_w;    d = wb + 262144;  rel = i - 262144; }
  else if (i < 786432)  { s = kv1_w;  d = wb + 524288;  rel = i - 524288; }
  else if (i < 1048576) { s = kv2_w;  d = wb + 786432;  rel = i - 786432; }
  else if (i < 1310720) { s = proj_w; d = wb + 1048576; rel = i - 1048576; }
  else                  { s = x;      d = xb;           rel = i - 1310720; }
  float4 v = *(const float4*)(s + rel);
  ushort4 o;
  o.x = f2bf(v.x); o.y = f2bf(v.y); o.z = f2bf(v.z); o.w = f2bf(v.w);
  *(ushort4*)(d + rel) = o;
}

// ---------------- paired bf16 MFMA GEMM (NT), blockIdx.z selects config
struct GPair {
  const unsigned short *A0, *A1, *B0, *B1;
  const float *bias0, *bias1;
  void *out0, *out1;
  int bf0, bf1;
  float sc0, sc1;
};

__global__ __launch_bounds__(256) void gemm_bf16(GPair p, int K, int Nn)
{
  const unsigned short* A  = blockIdx.z ? p.A1 : p.A0;
  const unsigned short* Bw = blockIdx.z ? p.B1 : p.B0;
  const float* bias        = blockIdx.z ? p.bias1 : p.bias0;
  void* out                = blockIdx.z ? p.out1 : p.out0;
  const int out_bf16       = blockIdx.z ? p.bf1 : p.bf0;
  const float oscale       = blockIdx.z ? p.sc1 : p.sc0;

  __shared__ unsigned short Abuf[128][40];
  __shared__ unsigned short Bbuf[128][40];
  const int tid = threadIdx.x;
  const int l = tid & 63, w = tid >> 6;
  const int wm = w >> 1, wn = w & 1;
  const int lo16 = l & 15, hi = l >> 4;
  const int row0 = blockIdx.x * 128, col0 = blockIdx.y * 128;
  const int srow = tid >> 2, scol = (tid & 3) * 8;

  f32x4 acc[4][4];
  #pragma unroll
  for (int m = 0; m < 4; ++m)
    #pragma unroll
    for (int n = 0; n < 4; ++n)
      #pragma unroll
      for (int r = 0; r < 4; ++r) acc[m][n][r] = 0.f;

  for (int k0 = 0; k0 < K; k0 += 32) {
    uint4 a0 = *(const uint4*)(A + (size_t)(row0 + srow) * K + k0 + scol);
    uint4 a1 = *(const uint4*)(A + (size_t)(row0 + 64 + srow) * K + k0 + scol);
    uint4 b0 = *(const uint4*)(Bw + (size_t)(col0 + srow) * K + k0 + scol);
    uint4 b1 = *(const uint4*)(Bw + (size_t)(col0 + 64 + srow) * K + k0 + scol);
    __syncthreads();
    *(uint4*)&Abuf[srow][scol]      = a0;
    *(uint4*)&Abuf[64 + srow][scol] = a1;
    *(uint4*)&Bbuf[srow][scol]      = b0;
    *(uint4*)&Bbuf[64 + srow][scol] = b1;
    __syncthreads();
    short8 af[4], bf[4];
    #pragma unroll
    for (int m = 0; m < 4; ++m)
      af[m] = *(const short8*)&Abuf[wm * 64 + m * 16 + lo16][hi * 8];
    #pragma unroll
    for (int n = 0; n < 4; ++n)
      bf[n] = *(const short8*)&Bbuf[wn * 64 + n * 16 + lo16][hi * 8];
    #pragma unroll
    for (int m = 0; m < 4; ++m)
      #pragma unroll
      for (int n = 0; n < 4; ++n)
        acc[m][n] = MFMA16(af[m], bf[n], acc[m][n]);
  }

  #pragma unroll
  for (int m = 0; m < 4; ++m) {
    #pragma unroll
    for (int n = 0; n < 4; ++n) {
      int gcol = col0 + wn * 64 + n * 16 + lo16;
      #pragma unroll
      for (int r = 0; r < 4; ++r) {
        int grow = row0 + wm * 64 + m * 16 + hi * 4 + r;
        float v = acc[m][n][r] + bias[gcol];
        if (out_bf16)
          ((unsigned short*)out)[(size_t)grow * Nn + gcol] = f2bf(v * oscale);
        else
          ((float*)out)[(size_t)grow * Nn + gcol] = v;
      }
    }
  }
}

// ---------------- depthwise 3x3 conv, channel-last [B,H,W,C] fp32
__global__ __launch_bounds__(256) void dwconv_kernel(
    const float* __restrict__ lin, const float* __restrict__ cw,
    const float* __restrict__ cb, float* __restrict__ outp)
{
  size_t gid = (size_t)blockIdx.x * blockDim.x + threadIdx.x;
  if (gid >= (size_t)B_ * N_ * C_) return;
  int c = (int)(gid % C_);
  size_t t = gid / C_;
  int wv = (int)(t % W_);
  size_t r = t / W_;
  int hv = (int)(r % H_);
  int b  = (int)(r / H_);
  float acc = cb[c];
  const float* wgt = cw + c * 9;
  #pragma unroll
  for (int dy = 0; dy < 3; ++dy) {
    int hh = hv + dy - 1;
    if (hh < 0 || hh >= H_) continue;
    #pragma unroll
    for (int dx = 0; dx < 3; ++dx) {
      int ww = wv + dx - 1;
      if (ww < 0 || ww >= W_) continue;
      acc += wgt[dy * 3 + dx] * lin[(((size_t)b * H_ + hh) * W_ + ww) * C_ + c];
    }
  }
  outp[gid] = acc;
}

// ---------------- stable argsort via rank counting
__global__ __launch_bounds__(256) void rank_argsort(
    const float* __restrict__ m1, const float* __restrict__ m2,
    int* __restrict__ i1, int* __restrict__ i2)
{
  __shared__ float key[N_];
  const int blk = blockIdx.x;
  const int row = blk / 36, chunk = blk % 36;
  const float* m = (row < 4) ? (m1 + (size_t)row * N_) : (m2 + (size_t)(row - 4) * N_);
  int* out = (row < 4) ? (i1 + (size_t)row * N_) : (i2 + (size_t)(row - 4) * N_);
  for (int i = threadIdx.x; i < N_ / 4; i += 256)
    ((float4*)key)[i] = ((const float4*)m)[i];
  __syncthreads();
  const int e = chunk * 64 + (threadIdx.x >> 2);
  const int sl = threadIdx.x & 3;
  const float ki = key[e];
  int rank = 0;
  #pragma unroll 4
  for (int t = 0; t < N_ / 16; ++t) {
    int jb = sl * 4 + t * 16;
    float4 kv = *(const float4*)&key[jb];
    rank += (kv.x < ki) || (kv.x == ki && jb     < e);
    rank += (kv.y < ki) || (kv.y == ki && jb + 1 < e);
    rank += (kv.z < ki) || (kv.z == ki && jb + 2 < e);
    rank += (kv.w < ki) || (kv.w == ki && jb + 3 < e);
  }
  rank += __shfl_xor(rank, 1);
  rank += __shfl_xor(rank, 2);
  if (sl == 0) out[rank] = e;
}

// ---------------- pooled sequences (both orderings in one launch)
__global__ __launch_bounds__(256) void pool_kernel(
    const float* __restrict__ ctx,
    const int* __restrict__ idx1, const int* __restrict__ idx2,
    const float* __restrict__ f1w, const float* __restrict__ f1b,
    const float* __restrict__ f2w, const float* __restrict__ f2b_,
    unsigned short* __restrict__ seqb1, unsigned short* __restrict__ seqb2)
{
  int bl = blockIdx.x;
  const int transposed = bl >= B_ * LKP_;
  if (transposed) bl -= B_ * LKP_;
  const int* idx = transposed ? idx2 : idx1;
  unsigned short* seqb = transposed ? seqb2 : seqb1;
  int b = bl / LKP_, l = bl % LKP_;
  unsigned short* dst = seqb + ((size_t)b * LKP_ + l) * C_;
  int c0 = threadIdx.x, c1 = threadIdx.x + 256;
  if (l >= LKV_) { dst[c0] = 0; dst[c1] = 0; return; }
  const int* id = idx + (size_t)b * N_;
  int j0, cnt;
  const float* fw; float fb;
  if (l < 12)       { j0 = l * 48;              cnt = 48; fw = f1w; fb = f1b[0]; }
  else if (l < 108) { j0 = 576 + (l - 12) * 12; cnt = 12; fw = f2w; fb = f2b_[0]; }
  else              { j0 = 1728 + (l - 108);    cnt = 1;  fw = nullptr; fb = 0.f; }
  const float* cb = ctx + (size_t)b * N_ * C_;
  float a0 = fb, a1 = fb;
  int r = 0;
  for (; r + 4 <= cnt; r += 4) {
    int4 nv = *(const int4*)(id + j0 + r);
    int n0 = nv.x, n1 = nv.y, n2 = nv.z, n3 = nv.w;
    if (transposed) {
      n0 = (n0 % 48) * 48 + n0 / 48; n1 = (n1 % 48) * 48 + n1 / 48;
      n2 = (n2 % 48) * 48 + n2 / 48; n3 = (n3 % 48) * 48 + n3 / 48;
    }
    const float* s0 = cb + (size_t)n0 * C_;
    const float* s1 = cb + (size_t)n1 * C_;
    const float* s2 = cb + (size_t)n2 * C_;
    const float* s3 = cb + (size_t)n3 * C_;
    float w0 = fw[r], w1 = fw[r+1], w2 = fw[r+2], w3 = fw[r+3];
    a0 += w0 * s0[c0] + w1 * s1[c0] + w2 * s2[c0] + w3 * s3[c0];
    a1 += w0 * s0[c1] + w1 * s1[c1] + w2 * s2[c1] + w3 * s3[c1];
  }
  for (; r < cnt; ++r) {
    int n = id[j0 + r];
    if (transposed) n = (n % 48) * 48 + n / 48;
    const float* src = cb + (size_t)n * C_;
    float wr = fw ? fw[r] : 1.f;
    a0 += wr * src[c0];
    a1 += wr * src[c1];
  }
  dst[c0] = f2bf(a0);
  dst[c1] = f2bf(a1);
}

// ---------------- kv -> MFMA fragment-major K and V buffers
// Kf/Vf layout: [(bh*11 + t)*8 + frag*2 + s][lane][8] shorts, lane = lo16 + 16*hi.
// Kf value: K[l = t*64 + frag*16 + lo16][d = s*32 + hi*8 + j]
// Vf value: V[l = t*64 + s*32 + hi*8 + j][d = frag*16 + lo16]
// Attention reads each fragment as 64 lanes x 16B contiguous (1 KB coalesced).
__global__ __launch_bounds__(256) void kvpack(
    const unsigned short* __restrict__ kv1, const unsigned short* __restrict__ kv2,
    unsigned short* __restrict__ Kf, unsigned short* __restrict__ Vf)
{
  __shared__ unsigned short Vt[64][72];
  const int bh = blockIdx.x / 11, t = blockIdx.x % 11;
  const int h = bh & 7, b = bh >> 3;
  const unsigned short* src = (h < 4) ? kv1 : kv2;
  const int hcol = (h & 3) * 64;
  const int tid = threadIdx.x;

  // stage V tile [64 rows][64 cols] into LDS (coalesced reads)
  #pragma unroll
  for (int pass = 0; pass < 2; ++pass) {
    int r = pass * 32 + (tid >> 3);
    int cc = (tid & 7) * 8;
    int l = t * 64 + r;
    uint4 v = make_uint4(0, 0, 0, 0);
    if (l < LKV_)
      v = *(const uint4*)&src[(size_t)(b * LKP_ + l) * C_ + 256 + hcol + cc];
    *(uint4*)&Vt[r][cc] = v;
  }
  __syncthreads();

  #pragma unroll
  for (int pass = 0; pass < 2; ++pass) {
    int o = pass * 256 + tid;            // (frag*2+s)*64 + lane
    int lane = o & 63, ns = o >> 6;
    int frag = ns >> 1, s = ns & 1;
    int lo16 = lane & 15, hi8 = (lane >> 4) * 8;
    size_t oidx = ((size_t)blockIdx.x * 8 + ns) * 512 + lane * 8;
    // K fragment (direct 16B read)
    {
      int l = t * 64 + frag * 16 + lo16;
      uint4 val = make_uint4(0, 0, 0, 0);
      if (l < LKV_)
        val = *(const uint4*)&src[(size_t)(b * LKP_ + l) * C_ + hcol + s * 32 + hi8];
      *(uint4*)&Kf[oidx] = val;
    }
    // V fragment (transposed gather from LDS)
    {
      unsigned short tmp[8];
      #pragma unroll
      for (int j = 0; j < 8; ++j)
        tmp[j] = Vt[s * 32 + hi8 + j][frag * 16 + lo16];
      *(uint4*)&Vf[oidx] = *(uint4*)tmp;
    }
  }
}

// ---------------- fused flash attention, bf16 MFMA, pipelined + coalesced
__global__ __launch_bounds__(256) void attn_kernel(
    const unsigned short* __restrict__ Qb, const unsigned short* __restrict__ Kf,
    const unsigned short* __restrict__ Vf, const float* __restrict__ lepe,
    unsigned short* __restrict__ outb)
{
  __shared__ unsigned short P[4][16][72];
  const int tid = threadIdx.x, l = tid & 63, wv = tid >> 6;
  const int lo16 = l & 15, hi = l >> 4;
  const int blk = blockIdx.x;
  const int qb = blk % (N_ / 64);
  const int bh = blk / (N_ / 64);
  const int h = bh & 7, b = bh >> 3;

  const int qrow = qb * 64 + wv * 16 + lo16;
  const unsigned short* qptr = Qb + ((size_t)b * N_ + qrow) * C_ + h * 64;
  short8 qf0 = *(const short8*)(qptr + hi * 8);
  short8 qf1 = *(const short8*)(qptr + 32 + hi * 8);

  // fragment-major bases: lane offset folded in; every load is 1KB coalesced
  const unsigned short* kbase = Kf + (size_t)bh * 11 * 4096 + (size_t)l * 8;
  const unsigned short* vbase = Vf + (size_t)bh * 11 * 4096 + (size_t)l * 8;

  float mreg[4], lsum[4];
  f32x4 o[4];
  #pragma unroll
  for (int r = 0; r < 4; ++r) { mreg[r] = -INFINITY; lsum[r] = 0.f; }
  #pragma unroll
  for (int df = 0; df < 4; ++df)
    #pragma unroll
    for (int r = 0; r < 4; ++r) o[df][r] = 0.f;

  // prologue: K tile 0
  short8 ka0[4], ka1[4], kn0[4], kn1[4];
  #pragma unroll
  for (int n = 0; n < 4; ++n) {
    ka0[n] = *(const short8*)(kbase + (n * 2 + 0) * 512);
    ka1[n] = *(const short8*)(kbase + (n * 2 + 1) * 512);
  }

  for (int t = 0; t < LKP_ / 64; ++t) {
    // V[t] issued early; latency hides under QK + softmax
    short8 vf0[4], vf1[4];
    #pragma unroll
    for (int df = 0; df < 4; ++df) {
      vf0[df] = *(const short8*)(vbase + (t * 8 + df * 2 + 0) * 512);
      vf1[df] = *(const short8*)(vbase + (t * 8 + df * 2 + 1) * 512);
    }
    // prefetch K[t+1]
    if (t < LKP_ / 64 - 1) {
      #pragma unroll
      for (int n = 0; n < 4; ++n) {
        kn0[n] = *(const short8*)(kbase + ((t + 1) * 8 + n * 2 + 0) * 512);
        kn1[n] = *(const short8*)(kbase + ((t + 1) * 8 + n * 2 + 1) * 512);
      }
    }
    f32x4 s[4];
    #pragma unroll
    for (int n = 0; n < 4; ++n) {
      #pragma unroll
      for (int r = 0; r < 4; ++r) s[n][r] = 0.f;
      s[n] = MFMA16(qf0, ka0[n], s[n]);
      s[n] = MFMA16(qf1, ka1[n], s[n]);
    }
    if (t == LKP_ / 64 - 1) {
      #pragma unroll
      for (int n = 0; n < 4; ++n)
        if (t * 64 + n * 16 + lo16 >= LKV_) {
          #pragma unroll
          for (int r = 0; r < 4; ++r) s[n][r] = -1e30f;
        }
    }
    float tm[4];
    #pragma unroll
    for (int r = 0; r < 4; ++r)
      tm[r] = fmaxf(fmaxf(s[0][r], s[1][r]), fmaxf(s[2][r], s[3][r]));
    #pragma unroll
    for (int off = 1; off <= 8; off <<= 1)
      #pragma unroll
      for (int r = 0; r < 4; ++r) tm[r] = fmaxf(tm[r], __shfl_xor(tm[r], off));
    float al[4];
    #pragma unroll
    for (int r = 0; r < 4; ++r) {
      float mn = fmaxf(mreg[r], tm[r]);
      al[r] = __expf(mreg[r] - mn);
      mreg[r] = mn;
    }
    float ps[4] = {0.f, 0.f, 0.f, 0.f};
    #pragma unroll
    for (int n = 0; n < 4; ++n)
      #pragma unroll
      for (int r = 0; r < 4; ++r) {
        float e = __expf(s[n][r] - mreg[r]);
        ps[r] += e;
        P[wv][hi * 4 + r][lo16 + 16 * n] = f2bf(e);
      }
    #pragma unroll
    for (int off = 1; off <= 8; off <<= 1)
      #pragma unroll
      for (int r = 0; r < 4; ++r) ps[r] += __shfl_xor(ps[r], off);
    #pragma unroll
    for (int r = 0; r < 4; ++r) lsum[r] = lsum[r] * al[r] + ps[r];
    #pragma unroll
    for (int df = 0; df < 4; ++df)
      #pragma unroll
      for (int r = 0; r < 4; ++r) o[df][r] *= al[r];
    short8 pa0 = *(const short8*)&P[wv][lo16][hi * 8];
    short8 pa1 = *(const short8*)&P[wv][lo16][32 + hi * 8];
    #pragma unroll
    for (int df = 0; df < 4; ++df) {
      o[df] = MFMA16(pa0, vf0[df], o[df]);
      o[df] = MFMA16(pa1, vf1[df], o[df]);
    }
    #pragma unroll
    for (int n = 0; n < 4; ++n) { ka0[n] = kn0[n]; ka1[n] = kn1[n]; }
  }

  float rinv[4];
  #pragma unroll
  for (int r = 0; r < 4; ++r) rinv[r] = 1.f / lsum[r];
  #pragma unroll
  for (int df = 0; df < 4; ++df)
    #pragma unroll
    for (int r = 0; r < 4; ++r) {
      size_t off = ((size_t)b * N_ + qb * 64 + wv * 16 + hi * 4 + r) * C_ + h * 64 + df * 16 + lo16;
      outb[off] = f2bf(o[df][r] * rinv[r] + lepe[off]);
    }
}

extern "C" void kernel_launch(void* const* d_in, const int* in_sizes, int n_in,
                              void* d_out, int out_size, void* d_ws, size_t ws_size,
                              hipStream_t stream)
{
  const float* x      = (const float*)d_in[0];
  const float* ctx    = (const float*)d_in[1];
  const float* mask1  = (const float*)d_in[2];
  const float* mask2  = (const float*)d_in[3];
  const float* q_w    = (const float*)d_in[4];
  const float* q_b    = (const float*)d_in[5];
  const float* kv1_w  = (const float*)d_in[6];
  const float* kv1_b  = (const float*)d_in[7];
  const float* kv2_w  = (const float*)d_in[8];
  const float* kv2_b  = (const float*)d_in[9];
  const float* f1_w   = (const float*)d_in[10];
  const float* f1_b   = (const float*)d_in[11];
  const float* f2_w   = (const float*)d_in[12];
  const float* f2_b   = (const float*)d_in[13];
  const float* lepe_w = (const float*)d_in[14];
  const float* lepe_b = (const float*)d_in[15];
  const float* lcw    = (const float*)d_in[16];
  const float* lcb    = (const float*)d_in[17];
  const float* proj_w = (const float*)d_in[18];
  const float* proj_b = (const float*)d_in[19];
  float* outp = (float*)d_out;

  char* ws = (char*)d_ws;
  float*          bufA  = (float*)(ws);                      // lepe-lin fp32
  float*          bufB  = (float*)(ws + 18874368);           // lepe fp32
  unsigned short* xb    = (unsigned short*)(ws + 37748736);  // x bf16 -> attn+lepe bf16
  unsigned short* Qb    = (unsigned short*)(ws + 47185920);
  unsigned short* wb    = (unsigned short*)(ws + 56623104);
  unsigned short* seqb1 = (unsigned short*)(ws + 59244544);
  unsigned short* seqb2 = (unsigned short*)(ws + 62128128);
  unsigned short* kv1b  = (unsigned short*)(ws + 65011712);
  unsigned short* kv2b  = (unsigned short*)(ws + 67895296);
  unsigned short* Kf    = (unsigned short*)(ws + 70778880);
  unsigned short* Vf    = (unsigned short*)(ws + 73662464);
  int*            idx1  = (int*)(ws + 76546048);
  int*            idx2  = (int*)(ws + 76582912);

  unsigned short* wb_lepe = wb;
  unsigned short* wb_q    = wb + 262144;
  unsigned short* wb_kv1  = wb + 524288;
  unsigned short* wb_kv2  = wb + 786432;
  unsigned short* wb_proj = wb + 1048576;

  dim3 blk(256);
  const int XN = B_ * N_ * C_;                 // 4,718,592
  const int PACKQ = (1310720 + XN) / 4 / 256;  // 5888 blocks

  pack_all<<<dim3(PACKQ), blk, 0, stream>>>(lepe_w, q_w, kv1_w, kv2_w, proj_w, x, wb, xb);
  rank_argsort<<<dim3(288), blk, 0, stream>>>(mask1, mask2, idx1, idx2);

  pool_kernel<<<dim3(2 * B_ * LKP_), blk, 0, stream>>>(
      ctx, idx1, idx2, f1_w, f1_b, f2_w, f2_b, seqb1, seqb2);

  // kv1 + kv2 projections in one launch
  {
    GPair p = { seqb1, seqb2, wb_kv1, wb_kv2, kv1_b, kv2_b,
                (void*)kv1b, (void*)kv2b, 1, 1, 1.f, 1.f };
    gemm_bf16<<<dim3(22, 4, 2), blk, 0, stream>>>(p, C_, C_);
  }
  // fragment-major K/V pack (one block per (bh, kv-tile))
  kvpack<<<dim3(32 * 11), blk, 0, stream>>>(kv1b, kv2b, Kf, Vf);

  // lepe linear (fp32 out) + q projection (bf16, folded 1/8 scale) in one launch
  {
    GPair p = { xb, xb, wb_lepe, wb_q, lepe_b, q_b,
                (void*)bufA, (void*)Qb, 0, 1, 1.f, 0.125f };
    gemm_bf16<<<dim3(72, 4, 2), blk, 0, stream>>>(p, C_, C_);
  }
  dwconv_kernel<<<dim3(XN / 256), blk, 0, stream>>>(bufA, lcw, lcb, bufB);

  // pipelined attention + (+lepe, ->bf16) epilogue, overwrites xb
  attn_kernel<<<dim3(B_ * NH_ * (N_ / 64)), blk, 0, stream>>>(Qb, Kf, Vf, bufB, xb);

  // final projection -> d_out fp32
  {
    GPair p = { xb, xb, wb_proj, wb_proj, proj_b, proj_b,
                (void*)outp, (void*)outp, 0, 0, 1.f, 1.f };
    gemm_bf16<<<dim3(72, 4, 1), blk, 0, stream>>>(p, C_, C_);
  }
}